// Round 10
// baseline (572.138 us; speedup 1.0000x reference)
//
#include <hip/hip_runtime.h>
#include <cstdint>

#define BN_EPS 1e-5f

typedef __attribute__((ext_vector_type(8))) short bf16x8;
typedef __attribute__((ext_vector_type(4))) float f32x4;
typedef __attribute__((ext_vector_type(2))) float f32x2;
typedef __attribute__((ext_vector_type(4))) unsigned int u32x4;
typedef unsigned int uint32;
typedef unsigned short u16;

__device__ inline u16 f2bf(float f) {
  unsigned int b = __float_as_uint(f);
  b += 0x7FFFu + ((b >> 16) & 1u);  // RNE
  return (u16)(b >> 16);
}
__device__ inline float bf2f(u16 u) { return __uint_as_float((unsigned int)u << 16); }

// ---------------- prep: pack weights + x->bf16 + x->fp8, one launch ----------------
// B1t [128 cols][288], B2t [64 cols][576] (bf16, row = out col).
// A-col index a: a<KT -> (i=a>>3, k=a&7) T-part (W[k,i,o]); a>=KT -> root/skip part.
// x8 [N][32] fp8 = 3.2 MB gather table (fits a 4 MiB per-XCD L2; bf16 xbf did not).
__global__ __launch_bounds__(256) void prep(const float* __restrict__ W1,
                                            const float* __restrict__ root1,
                                            const float* __restrict__ Wskip,
                                            const float* __restrict__ W2,
                                            const float* __restrict__ root2,
                                            u16* __restrict__ B1t, u16* __restrict__ B2t,
                                            const float* __restrict__ x,
                                            u16* __restrict__ xbf, uint32* __restrict__ x8,
                                            int total8) {
  int idx = blockIdx.x * 256 + threadIdx.x;
  if (idx < 128 * 288) {
    int n = idx / 288, a = idx % 288;
    float v;
    if (a < 256) {
      int i = a >> 3, k = a & 7;
      v = (n < 64) ? W1[k * 2048 + i * 64 + n] : 0.f;  // skip cols don't see T
    } else {
      int i = a - 256;
      v = (n < 64) ? root1[i * 64 + n] : Wskip[i * 64 + (n - 64)];
    }
    B1t[idx] = f2bf(v);
  } else if (idx < 128 * 288 + 64 * 576) {
    int j = idx - 128 * 288;
    int n = j / 576, a = j % 576;
    float v;
    if (a < 512) {
      int i = a >> 3, k = a & 7;
      v = W2[k * 4096 + i * 64 + n];
    } else {
      v = root2[(a - 512) * 64 + n];
    }
    B2t[j] = f2bf(v);
  }
  if (idx < total8) {
    const float4* xp = (const float4*)x;
    float4 a = xp[2 * idx], b = xp[2 * idx + 1];
    union { u16 s[8]; uint4 u; } p;
    p.s[0] = f2bf(a.x); p.s[1] = f2bf(a.y); p.s[2] = f2bf(a.z); p.s[3] = f2bf(a.w);
    p.s[4] = f2bf(b.x); p.s[5] = f2bf(b.y); p.s[6] = f2bf(b.z); p.s[7] = f2bf(b.w);
    ((uint4*)xbf)[idx] = p.u;
    uint32 w0 = (uint32)__builtin_amdgcn_cvt_pk_fp8_f32(a.x, a.y, 0, false);
    w0 = (uint32)__builtin_amdgcn_cvt_pk_fp8_f32(a.z, a.w, (int)w0, true);
    uint32 w1 = (uint32)__builtin_amdgcn_cvt_pk_fp8_f32(b.x, b.y, 0, false);
    w1 = (uint32)__builtin_amdgcn_cvt_pk_fp8_f32(b.z, b.w, (int)w1, true);
    x8[2 * idx + 0] = w0;
    x8[2 * idx + 1] = w1;
  }
}

// ---------------- dst-CSR build ----------------
// hist also records each edge's arrival rank within its dst segment: the atomic's
// return value. edge_scatter then needs NO atomic (pos = rowptr[dst] + rank[e]).
__global__ void hist_dst(const int* __restrict__ ei, int E, int* __restrict__ indeg,
                         int* __restrict__ rank) {
  int e = blockIdx.x * 256 + threadIdx.x;
  if (e >= E) return;
  rank[e] = atomicAdd(&indeg[ei[E + e]], 1);
}

__global__ __launch_bounds__(1024) void scan_block(const int* __restrict__ in,
                                                   int* __restrict__ part,
                                                   int* __restrict__ bsum, int N) {
  __shared__ int tmp[1024];
  int i = blockIdx.x * 1024 + threadIdx.x;
  int v = (i < N) ? in[i] : 0;
  tmp[threadIdx.x] = v;
  __syncthreads();
  for (int ofs = 1; ofs < 1024; ofs <<= 1) {
    int t = (threadIdx.x >= (unsigned)ofs) ? tmp[threadIdx.x - ofs] : 0;
    __syncthreads();
    tmp[threadIdx.x] += t;
    __syncthreads();
  }
  if (i < N) part[i] = tmp[threadIdx.x] - v;
  if (threadIdx.x == 1023) bsum[blockIdx.x] = tmp[1023];
}

__global__ __launch_bounds__(1024) void scan_top(int* __restrict__ bsum, int nb) {
  __shared__ int tmp[1024];
  int v = (threadIdx.x < (unsigned)nb) ? bsum[threadIdx.x] : 0;
  tmp[threadIdx.x] = v;
  __syncthreads();
  for (int ofs = 1; ofs < 1024; ofs <<= 1) {
    int t = (threadIdx.x >= (unsigned)ofs) ? tmp[threadIdx.x - ofs] : 0;
    __syncthreads();
    tmp[threadIdx.x] += t;
    __syncthreads();
  }
  if (threadIdx.x < (unsigned)nb) bsum[threadIdx.x] = tmp[threadIdx.x] - v;
}

__global__ void scan_add(const int* __restrict__ part, const int* __restrict__ bsum,
                         int* __restrict__ rowptr, int N, int E) {
  int i = blockIdx.x * 256 + threadIdx.x;
  if (i < N) rowptr[i] = part[i] + bsum[i >> 10];
  if (i == 0) rowptr[N] = E;
}

// Scatter: ONE 16-B record per edge: {src, fp16 u0|u1, fp16 u2|0, pad}.
// Position = rowptr[dst] + rank[e] (no atomic -> stores issue in bursts; partner
// quarter-lines co-reside in L2/L3 and merge: measured WRITE ~= payload).
// NOTE: keep these stores NORMAL (cached) — nt would break the L2 merging.
__global__ __launch_bounds__(256) void edge_scatter(const int* __restrict__ ei,
                                                    const float* __restrict__ attr,
                                                    const int* __restrict__ rowptr,
                                                    const int* __restrict__ rank, int E,
                                                    uint4* __restrict__ emeta) {
  int e = blockIdx.x * 256 + threadIdx.x;
  if (e >= E) return;
  int src = ei[e], dst = ei[E + e];
  union { _Float16 h[2]; uint32 u; } y, z;
  y.h[0] = (_Float16)attr[3 * e + 0];
  y.h[1] = (_Float16)attr[3 * e + 1];
  z.h[0] = (_Float16)attr[3 * e + 2];
  z.h[1] = (_Float16)0.f;
  int pos = rowptr[dst] + rank[e];
  emeta[pos] = make_uint4((uint32)src, y.u, z.u, 0u);
}

// ---------------- basis-first aggregation: T[dst][ch*8+k] = (1/deg) * sum_e w_k * tab[src][ch]
// 16 lanes per edge (p = lane&15), 4 edge-groups per wave (eh = lane>>4).
// PC channels per lane -> 16*PC channels: layer1 PC=2 fp8 [N][32] (3.2 MB, L2-fit),
// layer2 PC=4 fp8 [N][64]. emeta loads and T stores are NON-TEMPORAL so the streaming
// traffic doesn't evict the gather table from L2 (msg1 showed ~50 MB of table misses).
template <int PC, bool F8>
__device__ inline void sc_gather(const void* __restrict__ tab, int src, int p, float* xf) {
  if (F8 && PC == 4) {
    // 4 fp8 channels at byte offset 4p of a 64-B row
    uint32 u = *(const uint32*)((const char*)tab + (size_t)src * 64 + 4 * p);
    f32x2 a = __builtin_amdgcn_cvt_pk_f32_fp8((int)u, false);
    f32x2 b = __builtin_amdgcn_cvt_pk_f32_fp8((int)u, true);
    xf[0] = a.x; xf[1] = a.y; xf[2] = b.x; xf[3] = b.y;
  } else if (F8 && PC == 2) {
    // 2 fp8 channels at byte offset 2p of a 32-B row
    u16 us = *(const u16*)((const char*)tab + (size_t)src * 32 + 2 * p);
    f32x2 a = __builtin_amdgcn_cvt_pk_f32_fp8((int)us, false);
    xf[0] = a.x; xf[1] = a.y;
  } else {
    // 2 bf16 channels at channel 2p of a 32-ch row
    uint32 u = *(const uint32*)((const u16*)tab + (size_t)src * 32 + 2 * p);
    xf[0] = __uint_as_float(u << 16);
    xf[1] = __uint_as_float(u & 0xFFFF0000u);
  }
}

// Recompute the 8 trilinear basis weights from the packed fp16 attrs, then FMA.
template <int PC>
__device__ inline void sc_fma(float* acc, u32x4 m, const float* xf) {
  union { uint32 u; _Float16 h[2]; } cy, cz;
  cy.u = m.y;
  cz.u = m.z;
  float u0 = (float)cy.h[0], u1 = (float)cy.h[1], u2 = (float)cz.h[0];
  float p0 = 1.f - u0, p1 = 1.f - u1, p2 = 1.f - u2;
  float w00 = p1 * p2, w10 = u1 * p2, w01 = p1 * u2, w11 = u1 * u2;
  float w[8] = {p0 * w00, u0 * w00, p0 * w10, u0 * w10,
                p0 * w01, u0 * w01, p0 * w11, u0 * w11};
#pragma unroll
  for (int k = 0; k < 8; k++) {
#pragma unroll
    for (int c = 0; c < PC; c++) acc[k * PC + c] += w[k] * xf[c];
  }
}

template <int PC, bool F8>
__global__ __launch_bounds__(256) void msg_accum(const void* __restrict__ tab,
                                                 const int* __restrict__ rowptr,
                                                 const u32x4* __restrict__ emeta,
                                                 int n0, int n1, u16* __restrict__ T) {
  const int tid = threadIdx.x;
  const int lane = tid & 63;
  const int wv = tid >> 6;
  const int nwaves = gridDim.x * 4;
  const int p = lane & 15;
  const int eh = lane >> 4;  // 0..3

  for (int n = n0 + blockIdx.x * 4 + wv; n < n1; n += nwaves) {
    const int e0 = __builtin_amdgcn_readfirstlane(rowptr[n]);
    const int e1 = __builtin_amdgcn_readfirstlane(rowptr[n + 1]);
    float acc[8 * PC];
#pragma unroll
    for (int j = 0; j < 8 * PC; j++) acc[j] = 0.f;

    int e = e0;
    // 8 edges per iteration: 4 groups x 2 pairs -> 2 meta loads + 2 gathers in flight.
    for (; e + 8 <= e1; e += 8) {
      u32x4 a = __builtin_nontemporal_load(&emeta[e + eh]);
      u32x4 b = __builtin_nontemporal_load(&emeta[e + 4 + eh]);
      float xa[PC], xb[PC];
      sc_gather<PC, F8>(tab, (int)a.x, p, xa);
      sc_gather<PC, F8>(tab, (int)b.x, p, xb);
      sc_fma<PC>(acc, a, xa);
      sc_fma<PC>(acc, b, xb);
    }
    // tail: <=7 edges, masked quads
    for (; e < e1; e += 4) {
      int ee = e + eh;
      bool act = ee < e1;
      if (!act) ee = e;
      u32x4 m = __builtin_nontemporal_load(&emeta[ee]);
      float xv[PC];
      sc_gather<PC, F8>(tab, (int)m.x, p, xv);
      if (!act) {
#pragma unroll
        for (int c = 0; c < PC; c++) xv[c] = 0.f;
      }
      sc_fma<PC>(acc, m, xv);
    }

    // reduce across the 4 edge-groups
#pragma unroll
    for (int j = 0; j < 8 * PC; j++) {
      acc[j] += __shfl_xor(acc[j], 16);
      acc[j] += __shfl_xor(acc[j], 32);
    }

    float inv = 1.f / fmaxf((float)(e1 - e0), 1.f);
    if (eh == 0) {
      u16* rowp = T + (size_t)(n - n0) * (128 * PC);
#pragma unroll
      for (int c = 0; c < PC; c++) {
        union { u16 s[8]; u32x4 v; } pk;
#pragma unroll
        for (int k = 0; k < 8; k++) pk.s[k] = f2bf(acc[k * PC + c] * inv);
        __builtin_nontemporal_store(pk.v, (u32x4*)(rowp + ((size_t)(PC * p + c)) * 8));
      }
    }
  }
}

// ---------------- MFMA GEMM: out = [T | X] @ Bt^T, A all-bf16, output bf16 split at col 64.
// __launch_bounds__(256,3); afrag preloaded once (registers, nt load: T is read-once).
// Bt staged in LDS in two column halves (ds_read_b128 instead of ~200-cyc L2 hits).
// BN stats accumulated into sums via LDS + double atomics.
template <int KT, int KX, int NC>
__global__ __launch_bounds__(256, 3) void gemm_agg(const u16* __restrict__ T,
                                                   const u16* __restrict__ X,
                                                   const u16* __restrict__ Bt,
                                                   u16* __restrict__ O1, u16* __restrict__ O2,
                                                   int rowOff, int rows,
                                                   double* __restrict__ sums) {
  const int K = KT + KX;
  const int KP = K + 8;     // padded LDS row stride (u16 units)
  const int NCH = NC / 2;   // staged columns per half
  const int tid = threadIdx.x;
  const int lane = tid & 63;
  const int wv = tid >> 6;
  const int rowbase = blockIdx.x * 64 + wv * 16;
  const int m = lane & 15;
  const int quad = lane >> 4;
  const int k0 = quad * 8;

  __shared__ u16 bs[NCH * (KT + KX + 8)];
  __shared__ float slds[4][NC][2];

  int ar = rowbase + m;
  if (ar > rows - 1) ar = rows - 1;

  bf16x8 afrag[K / 32];
#pragma unroll
  for (int f = 0; f < K / 32; f++) {
    if (f * 32 < KT)
      afrag[f] = __builtin_nontemporal_load(
          (const bf16x8*)(T + (size_t)ar * KT + f * 32 + k0));
    else
      afrag[f] = *(const bf16x8*)(X + (size_t)(rowOff + ar) * KX + (f * 32 - KT) + k0);
  }

  for (int halfc = 0; halfc < 2; halfc++) {
    __syncthreads();  // prior-half readers done before overwrite (no-op cost on 1st)
    for (int i = tid; i < NCH * (K / 8); i += 256) {
      int col = i / (K / 8);
      int kk = (i % (K / 8)) * 8;
      *(uint4*)(bs + col * KP + kk) =
          *(const uint4*)(Bt + (size_t)(halfc * NCH + col) * K + kk);
    }
    __syncthreads();

    for (int col0 = 0; col0 < NCH; col0 += 32) {
      f32x4 acc0 = {0.f, 0.f, 0.f, 0.f};
      f32x4 acc1 = {0.f, 0.f, 0.f, 0.f};
#pragma unroll
      for (int f = 0; f < K / 32; f++) {
        bf16x8 b0 = *(const bf16x8*)(bs + (col0 + m) * KP + f * 32 + k0);
        bf16x8 b1 = *(const bf16x8*)(bs + (col0 + 16 + m) * KP + f * 32 + k0);
        acc0 = __builtin_amdgcn_mfma_f32_16x16x32_bf16(afrag[f], b0, acc0, 0, 0, 0);
        acc1 = __builtin_amdgcn_mfma_f32_16x16x32_bf16(afrag[f], b1, acc1, 0, 0, 0);
      }
#pragma unroll
      for (int half = 0; half < 2; half++) {
        const f32x4& acc = half ? acc1 : acc0;
        const int col = halfc * NCH + col0 + half * 16 + m;
        float s1 = 0.f, s2 = 0.f;
#pragma unroll
        for (int r = 0; r < 4; r++) {
          int gr = rowbase + quad * 4 + r;
          if (gr < rows) {
            size_t g = (size_t)(rowOff + gr);
            u16 vq = f2bf(acc[r]);
            float v = bf2f(vq);
            s1 += v;
            s2 += v * v;
            if (NC == 64 || col < 64) O1[g * 64 + col] = vq;
            else O2[g * 64 + (col - 64)] = vq;
          }
        }
        // reduce the 64 block-rows for this col: quads live at lane m+16q
        s1 += __shfl_xor(s1, 16); s1 += __shfl_xor(s1, 32);
        s2 += __shfl_xor(s2, 16); s2 += __shfl_xor(s2, 32);
        if (lane < 16) { slds[wv][col][0] = s1; slds[wv][col][1] = s2; }
      }
    }
  }
  __syncthreads();
  if (tid < NC * 2) {
    int col = tid >> 1, which = tid & 1;
    float v = slds[0][col][which] + slds[1][col][which] + slds[2][col][which] +
              slds[3][col][which];
    int slot = ((NC > 64 && col >= 64) ? 128 : 0) + which * 64 + (col & 63);
    atomicAdd(&sums[slot], (double)v);
  }
}

// ---------------- bn finalize: one or two parameter sets per launch ----------------
__global__ void bn_finalize2(const double* __restrict__ sums, const float* __restrict__ gA,
                             const float* __restrict__ bA, const float* __restrict__ gB,
                             const float* __restrict__ bB, float* __restrict__ scales, int N) {
  int t = threadIdx.x;
  int set = t >> 6, ch = t & 63;
  if (set == 1 && gB == nullptr) return;
  const float* g = set ? gB : gA;
  const float* b = set ? bB : bA;
  double mean = sums[set * 128 + ch] / (double)N;
  double var = sums[set * 128 + 64 + ch] / (double)N - mean * mean;
  double inv = 1.0 / sqrt(var + (double)BN_EPS);
  float sc = (float)((double)g[ch] * inv);
  scales[set * 128 + ch] = sc;
  scales[set * 128 + 64 + ch] = b[ch] - (float)mean * sc;
}

// ---------------- h1pre -> elu(bn1(h1pre)) in place (bf16, gemm2's A tail) + fp8 copy
// h8 [N][64] (layer-2 gather table: 6.4 MB). 2 channels/thread.
__global__ __launch_bounds__(256) void bn_elu_inplace(u16* __restrict__ h,
                                                      u16* __restrict__ h8,
                                                      const float* __restrict__ sc,
                                                      int total2) {
  int idx = blockIdx.x * 256 + threadIdx.x;
  if (idx >= total2) return;
  int ch = (idx * 2) & 63;
  uint32 u = ((const uint32*)h)[idx];
  float v0 = __uint_as_float(u << 16);
  float v1 = __uint_as_float(u & 0xFFFF0000u);
  v0 = v0 * sc[ch] + sc[64 + ch];
  v1 = v1 * sc[ch + 1] + sc[64 + ch + 1];
  v0 = v0 > 0.f ? v0 : expm1f(v0);
  v1 = v1 > 0.f ? v1 : expm1f(v1);
  ((uint32*)h)[idx] = ((uint32)f2bf(v1) << 16) | (uint32)f2bf(v0);
  int p8 = __builtin_amdgcn_cvt_pk_fp8_f32(v0, v1, 0, false);  // byte0=v0, byte1=v1
  h8[idx] = (u16)(p8 & 0xFFFF);
}

// ---------------- epilogue: out = elu(bn2(h2pre) + bnS(skip)) ----------------
__global__ __launch_bounds__(256) void final_k(const u16* __restrict__ h2pre,
                                               const u16* __restrict__ skip,
                                               const float* __restrict__ sc2,
                                               const float* __restrict__ scS,
                                               float* __restrict__ out, int total) {
  int idx = blockIdx.x * 256 + threadIdx.x;
  if (idx >= total) return;
  int ch = idx & 63;
  float h2 = bf2f(h2pre[idx]) * sc2[ch] + sc2[64 + ch];
  float s = bf2f(skip[idx]) * scS[ch] + scS[64 + ch];
  float v = h2 + s;
  out[idx] = v > 0.f ? v : expm1f(v);
}

extern "C" void kernel_launch(void* const* d_in, const int* in_sizes, int n_in,
                              void* d_out, int out_size, void* d_ws, size_t ws_size,
                              hipStream_t stream) {
  const float* x     = (const float*)d_in[0];
  const int*   ei    = (const int*)d_in[1];
  const float* attr  = (const float*)d_in[2];
  const float* W1    = (const float*)d_in[3];
  const float* root1 = (const float*)d_in[4];
  const float* g1    = (const float*)d_in[5];
  const float* b1    = (const float*)d_in[6];
  const float* W2    = (const float*)d_in[7];
  const float* root2 = (const float*)d_in[8];
  const float* g2    = (const float*)d_in[9];
  const float* b2    = (const float*)d_in[10];
  const float* Wskip = (const float*)d_in[11];
  const float* gS    = (const float*)d_in[12];
  const float* bS    = (const float*)d_in[13];
  const int N = in_sizes[0] / 32;
  const int E = in_sizes[1] / 2;
  const int Nh = (N + 1) / 2;
  float* out = (float*)d_out;

  char* ws = (char*)d_ws;
  size_t off = 0;
  auto alloc = [&](size_t bytes) {
    void* p = ws + off;
    off = (off + bytes + 255) & ~(size_t)255;
    return p;
  };
  u16* B1t = (u16*)alloc(128 * 288 * 2);
  u16* B2t = (u16*)alloc(64 * 576 * 2);
  double* sums = (double*)alloc(6 * 64 * 8);    // [h1 | skip | h2] x {sum, sumsq}
  float* scales = (float*)alloc(6 * 64 * 4);    // [bn1 | bnS | bn2] x {scale, shift}
  int* indeg = (int*)alloc((size_t)N * 4);
  int* rowptr = (int*)alloc(((size_t)N + 1) * 4);
  int* part = (int*)alloc((size_t)N * 4);
  int* bsum = (int*)alloc(1024 * 4);
  int* rank = (int*)alloc((size_t)E * 4);                  // per-edge rank within dst
  uint4* emeta = (uint4*)alloc((size_t)E * 16);            // {src, fp16 u0|u1, fp16 u2, pad}
  u16* xbf = (u16*)alloc((size_t)N * 32 * 2);              // bf16 x (GEMM1 A-tail)
  uint32* x8 = (uint32*)alloc((size_t)N * 32);             // fp8 x (layer-1 gather, 3.2 MB)
  u16* h8 = (u16*)alloc((size_t)N * 64);                   // fp8 h1 (layer-2 gather table)
  u16* T = (u16*)alloc((size_t)(N + 2) * 256 * 2);         // T1 full [N][256] / T2 chunk [Nh][512]
  u16* h1 = (u16*)alloc((size_t)N * 64 * 2);               // h1pre -> elu(bn1()) in place
  u16* skip = (u16*)alloc((size_t)N * 64 * 2);             // x@Wskip (pre-BN)
  u16* h2 = (u16*)alloc((size_t)N * 64 * 2);               // h2pre
  if (off > ws_size) return;  // workspace too small: fail gracefully

  hipMemsetAsync(indeg, 0, (size_t)N * 4, stream);
  hipMemsetAsync(sums, 0, 6 * 64 * 8, stream);

  const int eblocks = (E + 255) / 256;
  const int nb = (N + 1023) / 1024;
  prep<<<(N * 4 + 255) / 256, 256, 0, stream>>>(W1, root1, Wskip, W2, root2, B1t, B2t,
                                                x, xbf, x8, N * 4);
  hist_dst<<<eblocks, 256, 0, stream>>>(ei, E, indeg, rank);
  scan_block<<<nb, 1024, 0, stream>>>(indeg, part, bsum, N);
  scan_top<<<1, 1024, 0, stream>>>(bsum, nb);
  scan_add<<<(N + 255) / 256, 256, 0, stream>>>(part, bsum, rowptr, N, E);
  edge_scatter<<<eblocks, 256, 0, stream>>>(ei, attr, rowptr, rank, E, emeta);

  // ---- layer 1: T1 = basis-weighted fp8-x aggregation; h1/skip = [T1 | xbf] @ B1t
  msg_accum<2, true><<<2048, 256, 0, stream>>>(x8, rowptr, (const u32x4*)emeta, 0, N, T);
  gemm_agg<256, 32, 128><<<(N + 63) / 64, 256, 0, stream>>>(T, xbf, B1t, h1, skip, 0, N,
                                                            sums);
  bn_finalize2<<<1, 128, 0, stream>>>(sums, g1, b1, gS, bS, scales, N);  // bn1 + bnS
  bn_elu_inplace<<<(N * 32 + 255) / 256, 256, 0, stream>>>(h1, h8, scales, N * 32);

  // ---- layer 2 in two row-chunks (T2 chunk buffer = 51.2 MB); gathers fp8 h8 ----
  for (int cph = 0; cph < 2; cph++) {
    int r0 = cph ? Nh : 0;
    int r1 = cph ? N : Nh;
    msg_accum<4, true><<<2048, 256, 0, stream>>>(h8, rowptr, (const u32x4*)emeta, r0, r1, T);
    gemm_agg<512, 64, 64><<<(r1 - r0 + 63) / 64, 256, 0, stream>>>(T, h1, B2t, h2, nullptr,
                                                                   r0, r1 - r0,
                                                                   sums + 4 * 64);
  }
  bn_finalize2<<<1, 64, 0, stream>>>(sums + 4 * 64, g2, b2, nullptr, nullptr,
                                     scales + 4 * 64, N);

  final_k<<<(N * 64 + 255) / 256, 256, 0, stream>>>(h2, skip, scales + 4 * 64,
                                                    scales + 2 * 64, out, N * 64);
}

// Round 11
// 569.970 us; speedup vs baseline: 1.0038x; 1.0038x over previous
//
#include <hip/hip_runtime.h>
#include <cstdint>

#define BN_EPS 1e-5f

typedef __attribute__((ext_vector_type(8))) short bf16x8;
typedef __attribute__((ext_vector_type(4))) float f32x4;
typedef __attribute__((ext_vector_type(2))) float f32x2;
typedef __attribute__((ext_vector_type(4))) unsigned int u32x4;
typedef unsigned int uint32;
typedef unsigned short u16;

__device__ inline u16 f2bf(float f) {
  unsigned int b = __float_as_uint(f);
  b += 0x7FFFu + ((b >> 16) & 1u);  // RNE
  return (u16)(b >> 16);
}
__device__ inline float bf2f(u16 u) { return __uint_as_float((unsigned int)u << 16); }

// ---------------- prep: pack weights + x->bf16 + x->fp8, one launch ----------------
// B1t [128 cols][288], B2t [64 cols][576] (bf16, row = out col).
// A-col index a: a<KT -> (i=a>>3, k=a&7) T-part (W[k,i,o]); a>=KT -> root/skip part.
// x8 [N][32] fp8 = 3.2 MB gather table (fits a 4 MiB per-XCD L2; bf16 xbf did not).
__global__ __launch_bounds__(256) void prep(const float* __restrict__ W1,
                                            const float* __restrict__ root1,
                                            const float* __restrict__ Wskip,
                                            const float* __restrict__ W2,
                                            const float* __restrict__ root2,
                                            u16* __restrict__ B1t, u16* __restrict__ B2t,
                                            const float* __restrict__ x,
                                            u16* __restrict__ xbf, uint32* __restrict__ x8,
                                            int total8) {
  int idx = blockIdx.x * 256 + threadIdx.x;
  if (idx < 128 * 288) {
    int n = idx / 288, a = idx % 288;
    float v;
    if (a < 256) {
      int i = a >> 3, k = a & 7;
      v = (n < 64) ? W1[k * 2048 + i * 64 + n] : 0.f;  // skip cols don't see T
    } else {
      int i = a - 256;
      v = (n < 64) ? root1[i * 64 + n] : Wskip[i * 64 + (n - 64)];
    }
    B1t[idx] = f2bf(v);
  } else if (idx < 128 * 288 + 64 * 576) {
    int j = idx - 128 * 288;
    int n = j / 576, a = j % 576;
    float v;
    if (a < 512) {
      int i = a >> 3, k = a & 7;
      v = W2[k * 4096 + i * 64 + n];
    } else {
      v = root2[(a - 512) * 64 + n];
    }
    B2t[j] = f2bf(v);
  }
  if (idx < total8) {
    const float4* xp = (const float4*)x;
    float4 a = xp[2 * idx], b = xp[2 * idx + 1];
    union { u16 s[8]; uint4 u; } p;
    p.s[0] = f2bf(a.x); p.s[1] = f2bf(a.y); p.s[2] = f2bf(a.z); p.s[3] = f2bf(a.w);
    p.s[4] = f2bf(b.x); p.s[5] = f2bf(b.y); p.s[6] = f2bf(b.z); p.s[7] = f2bf(b.w);
    ((uint4*)xbf)[idx] = p.u;
    uint32 w0 = (uint32)__builtin_amdgcn_cvt_pk_fp8_f32(a.x, a.y, 0, false);
    w0 = (uint32)__builtin_amdgcn_cvt_pk_fp8_f32(a.z, a.w, (int)w0, true);
    uint32 w1 = (uint32)__builtin_amdgcn_cvt_pk_fp8_f32(b.x, b.y, 0, false);
    w1 = (uint32)__builtin_amdgcn_cvt_pk_fp8_f32(b.z, b.w, (int)w1, true);
    x8[2 * idx + 0] = w0;
    x8[2 * idx + 1] = w1;
  }
}

// ---------------- dst-CSR build ----------------
// hist also records each edge's arrival rank within its dst segment: the atomic's
// return value. edge_scatter then needs NO atomic (pos = rowptr[dst] + rank[e]).
__global__ void hist_dst(const int* __restrict__ ei, int E, int* __restrict__ indeg,
                         int* __restrict__ rank) {
  int e = blockIdx.x * 256 + threadIdx.x;
  if (e >= E) return;
  rank[e] = atomicAdd(&indeg[ei[E + e]], 1);
}

__global__ __launch_bounds__(1024) void scan_block(const int* __restrict__ in,
                                                   int* __restrict__ part,
                                                   int* __restrict__ bsum, int N) {
  __shared__ int tmp[1024];
  int i = blockIdx.x * 1024 + threadIdx.x;
  int v = (i < N) ? in[i] : 0;
  tmp[threadIdx.x] = v;
  __syncthreads();
  for (int ofs = 1; ofs < 1024; ofs <<= 1) {
    int t = (threadIdx.x >= (unsigned)ofs) ? tmp[threadIdx.x - ofs] : 0;
    __syncthreads();
    tmp[threadIdx.x] += t;
    __syncthreads();
  }
  if (i < N) part[i] = tmp[threadIdx.x] - v;
  if (threadIdx.x == 1023) bsum[blockIdx.x] = tmp[1023];
}

__global__ __launch_bounds__(1024) void scan_top(int* __restrict__ bsum, int nb) {
  __shared__ int tmp[1024];
  int v = (threadIdx.x < (unsigned)nb) ? bsum[threadIdx.x] : 0;
  tmp[threadIdx.x] = v;
  __syncthreads();
  for (int ofs = 1; ofs < 1024; ofs <<= 1) {
    int t = (threadIdx.x >= (unsigned)ofs) ? tmp[threadIdx.x - ofs] : 0;
    __syncthreads();
    tmp[threadIdx.x] += t;
    __syncthreads();
  }
  if (threadIdx.x < (unsigned)nb) bsum[threadIdx.x] = tmp[threadIdx.x] - v;
}

__global__ void scan_add(const int* __restrict__ part, const int* __restrict__ bsum,
                         int* __restrict__ rowptr, int N, int E) {
  int i = blockIdx.x * 256 + threadIdx.x;
  if (i < N) rowptr[i] = part[i] + bsum[i >> 10];
  if (i == 0) rowptr[N] = E;
}

// Scatter: ONE 16-B record per edge: {src, fp16 u0|u1, fp16 u2|0, pad}.
// Position = rowptr[dst] + rank[e] (no atomic -> stores issue in bursts; partner
// quarter-lines co-reside in L2/L3 and merge: measured WRITE ~= payload).
// NOTE: keep these stores NORMAL (cached) — nt would break the L2 merging.
__global__ __launch_bounds__(256) void edge_scatter(const int* __restrict__ ei,
                                                    const float* __restrict__ attr,
                                                    const int* __restrict__ rowptr,
                                                    const int* __restrict__ rank, int E,
                                                    uint4* __restrict__ emeta) {
  int e = blockIdx.x * 256 + threadIdx.x;
  if (e >= E) return;
  int src = ei[e], dst = ei[E + e];
  union { _Float16 h[2]; uint32 u; } y, z;
  y.h[0] = (_Float16)attr[3 * e + 0];
  y.h[1] = (_Float16)attr[3 * e + 1];
  z.h[0] = (_Float16)attr[3 * e + 2];
  z.h[1] = (_Float16)0.f;
  int pos = rowptr[dst] + rank[e];
  emeta[pos] = make_uint4((uint32)src, y.u, z.u, 0u);
}

// ---------------- basis-first aggregation: T[dst][ch*8+k] = (1/deg) * sum_e w_k * tab[src][ch]
// 16 lanes per edge (p = lane&15), 4 edge-groups per wave (eh = lane>>4).
// PC channels per lane -> 16*PC channels: layer1 PC=2 fp8 [N][32] (3.2 MB, L2-fit),
// layer2 PC=4 fp8 [N][64]. emeta loads are NON-TEMPORAL (read-once stream; protects the
// gather table's L2 residency — msg1 FETCH 75.7->33.2 MB measured). T stores stay NORMAL:
// round-10's nt T-stores caused 2x write amplification (partial lines evicted early) and
// evicted T before gemm_agg read it (-43 us elsewhere).
template <int PC, bool F8>
__device__ inline void sc_gather(const void* __restrict__ tab, int src, int p, float* xf) {
  if (F8 && PC == 4) {
    // 4 fp8 channels at byte offset 4p of a 64-B row
    uint32 u = *(const uint32*)((const char*)tab + (size_t)src * 64 + 4 * p);
    f32x2 a = __builtin_amdgcn_cvt_pk_f32_fp8((int)u, false);
    f32x2 b = __builtin_amdgcn_cvt_pk_f32_fp8((int)u, true);
    xf[0] = a.x; xf[1] = a.y; xf[2] = b.x; xf[3] = b.y;
  } else if (F8 && PC == 2) {
    // 2 fp8 channels at byte offset 2p of a 32-B row
    u16 us = *(const u16*)((const char*)tab + (size_t)src * 32 + 2 * p);
    f32x2 a = __builtin_amdgcn_cvt_pk_f32_fp8((int)us, false);
    xf[0] = a.x; xf[1] = a.y;
  } else {
    // 2 bf16 channels at channel 2p of a 32-ch row
    uint32 u = *(const uint32*)((const u16*)tab + (size_t)src * 32 + 2 * p);
    xf[0] = __uint_as_float(u << 16);
    xf[1] = __uint_as_float(u & 0xFFFF0000u);
  }
}

// Recompute the 8 trilinear basis weights from the packed fp16 attrs, then FMA.
template <int PC>
__device__ inline void sc_fma(float* acc, u32x4 m, const float* xf) {
  union { uint32 u; _Float16 h[2]; } cy, cz;
  cy.u = m.y;
  cz.u = m.z;
  float u0 = (float)cy.h[0], u1 = (float)cy.h[1], u2 = (float)cz.h[0];
  float p0 = 1.f - u0, p1 = 1.f - u1, p2 = 1.f - u2;
  float w00 = p1 * p2, w10 = u1 * p2, w01 = p1 * u2, w11 = u1 * u2;
  float w[8] = {p0 * w00, u0 * w00, p0 * w10, u0 * w10,
                p0 * w01, u0 * w01, p0 * w11, u0 * w11};
#pragma unroll
  for (int k = 0; k < 8; k++) {
#pragma unroll
    for (int c = 0; c < PC; c++) acc[k * PC + c] += w[k] * xf[c];
  }
}

template <int PC, bool F8>
__global__ __launch_bounds__(256) void msg_accum(const void* __restrict__ tab,
                                                 const int* __restrict__ rowptr,
                                                 const u32x4* __restrict__ emeta,
                                                 int n0, int n1, u16* __restrict__ T) {
  const int tid = threadIdx.x;
  const int lane = tid & 63;
  const int wv = tid >> 6;
  const int nwaves = gridDim.x * 4;
  const int p = lane & 15;
  const int eh = lane >> 4;  // 0..3

  for (int n = n0 + blockIdx.x * 4 + wv; n < n1; n += nwaves) {
    const int e0 = __builtin_amdgcn_readfirstlane(rowptr[n]);
    const int e1 = __builtin_amdgcn_readfirstlane(rowptr[n + 1]);
    float acc[8 * PC];
#pragma unroll
    for (int j = 0; j < 8 * PC; j++) acc[j] = 0.f;

    int e = e0;
    // 8 edges per iteration: 4 groups x 2 pairs -> 2 meta loads + 2 gathers in flight.
    for (; e + 8 <= e1; e += 8) {
      u32x4 a = __builtin_nontemporal_load(&emeta[e + eh]);
      u32x4 b = __builtin_nontemporal_load(&emeta[e + 4 + eh]);
      float xa[PC], xb[PC];
      sc_gather<PC, F8>(tab, (int)a.x, p, xa);
      sc_gather<PC, F8>(tab, (int)b.x, p, xb);
      sc_fma<PC>(acc, a, xa);
      sc_fma<PC>(acc, b, xb);
    }
    // tail: <=7 edges, masked quads
    for (; e < e1; e += 4) {
      int ee = e + eh;
      bool act = ee < e1;
      if (!act) ee = e;
      u32x4 m = __builtin_nontemporal_load(&emeta[ee]);
      float xv[PC];
      sc_gather<PC, F8>(tab, (int)m.x, p, xv);
      if (!act) {
#pragma unroll
        for (int c = 0; c < PC; c++) xv[c] = 0.f;
      }
      sc_fma<PC>(acc, m, xv);
    }

    // reduce across the 4 edge-groups
#pragma unroll
    for (int j = 0; j < 8 * PC; j++) {
      acc[j] += __shfl_xor(acc[j], 16);
      acc[j] += __shfl_xor(acc[j], 32);
    }

    float inv = 1.f / fmaxf((float)(e1 - e0), 1.f);
    if (eh == 0) {
      u16* rowp = T + (size_t)(n - n0) * (128 * PC);
#pragma unroll
      for (int c = 0; c < PC; c++) {
        union { u16 s[8]; uint4 u; } pk;
#pragma unroll
        for (int k = 0; k < 8; k++) pk.s[k] = f2bf(acc[k * PC + c] * inv);
        *(uint4*)(rowp + ((size_t)(PC * p + c)) * 8) = pk.u;
      }
    }
  }
}

// ---------------- MFMA GEMM: out = [T | X] @ Bt^T, A all-bf16, output bf16 split at col 64.
// __launch_bounds__(256,3); afrag preloaded once into registers (normal loads: T is
// L2-warm from msg_accum's cached stores). Bt staged in LDS in two column halves
// (ds_read_b128 instead of ~200-cyc L2 hits). BN stats via LDS + double atomics.
template <int KT, int KX, int NC>
__global__ __launch_bounds__(256, 3) void gemm_agg(const u16* __restrict__ T,
                                                   const u16* __restrict__ X,
                                                   const u16* __restrict__ Bt,
                                                   u16* __restrict__ O1, u16* __restrict__ O2,
                                                   int rowOff, int rows,
                                                   double* __restrict__ sums) {
  const int K = KT + KX;
  const int KP = K + 8;     // padded LDS row stride (u16 units)
  const int NCH = NC / 2;   // staged columns per half
  const int tid = threadIdx.x;
  const int lane = tid & 63;
  const int wv = tid >> 6;
  const int rowbase = blockIdx.x * 64 + wv * 16;
  const int m = lane & 15;
  const int quad = lane >> 4;
  const int k0 = quad * 8;

  __shared__ u16 bs[NCH * (KT + KX + 8)];
  __shared__ float slds[4][NC][2];

  int ar = rowbase + m;
  if (ar > rows - 1) ar = rows - 1;

  bf16x8 afrag[K / 32];
#pragma unroll
  for (int f = 0; f < K / 32; f++) {
    if (f * 32 < KT)
      afrag[f] = *(const bf16x8*)(T + (size_t)ar * KT + f * 32 + k0);
    else
      afrag[f] = *(const bf16x8*)(X + (size_t)(rowOff + ar) * KX + (f * 32 - KT) + k0);
  }

  for (int halfc = 0; halfc < 2; halfc++) {
    __syncthreads();  // prior-half readers done before overwrite (no-op cost on 1st)
    for (int i = tid; i < NCH * (K / 8); i += 256) {
      int col = i / (K / 8);
      int kk = (i % (K / 8)) * 8;
      *(uint4*)(bs + col * KP + kk) =
          *(const uint4*)(Bt + (size_t)(halfc * NCH + col) * K + kk);
    }
    __syncthreads();

    for (int col0 = 0; col0 < NCH; col0 += 32) {
      f32x4 acc0 = {0.f, 0.f, 0.f, 0.f};
      f32x4 acc1 = {0.f, 0.f, 0.f, 0.f};
#pragma unroll
      for (int f = 0; f < K / 32; f++) {
        bf16x8 b0 = *(const bf16x8*)(bs + (col0 + m) * KP + f * 32 + k0);
        bf16x8 b1 = *(const bf16x8*)(bs + (col0 + 16 + m) * KP + f * 32 + k0);
        acc0 = __builtin_amdgcn_mfma_f32_16x16x32_bf16(afrag[f], b0, acc0, 0, 0, 0);
        acc1 = __builtin_amdgcn_mfma_f32_16x16x32_bf16(afrag[f], b1, acc1, 0, 0, 0);
      }
#pragma unroll
      for (int half = 0; half < 2; half++) {
        const f32x4& acc = half ? acc1 : acc0;
        const int col = halfc * NCH + col0 + half * 16 + m;
        float s1 = 0.f, s2 = 0.f;
#pragma unroll
        for (int r = 0; r < 4; r++) {
          int gr = rowbase + quad * 4 + r;
          if (gr < rows) {
            size_t g = (size_t)(rowOff + gr);
            u16 vq = f2bf(acc[r]);
            float v = bf2f(vq);
            s1 += v;
            s2 += v * v;
            if (NC == 64 || col < 64) O1[g * 64 + col] = vq;
            else O2[g * 64 + (col - 64)] = vq;
          }
        }
        // reduce the 64 block-rows for this col: quads live at lane m+16q
        s1 += __shfl_xor(s1, 16); s1 += __shfl_xor(s1, 32);
        s2 += __shfl_xor(s2, 16); s2 += __shfl_xor(s2, 32);
        if (lane < 16) { slds[wv][col][0] = s1; slds[wv][col][1] = s2; }
      }
    }
  }
  __syncthreads();
  if (tid < NC * 2) {
    int col = tid >> 1, which = tid & 1;
    float v = slds[0][col][which] + slds[1][col][which] + slds[2][col][which] +
              slds[3][col][which];
    int slot = ((NC > 64 && col >= 64) ? 128 : 0) + which * 64 + (col & 63);
    atomicAdd(&sums[slot], (double)v);
  }
}

// ---------------- bn finalize: one or two parameter sets per launch ----------------
__global__ void bn_finalize2(const double* __restrict__ sums, const float* __restrict__ gA,
                             const float* __restrict__ bA, const float* __restrict__ gB,
                             const float* __restrict__ bB, float* __restrict__ scales, int N) {
  int t = threadIdx.x;
  int set = t >> 6, ch = t & 63;
  if (set == 1 && gB == nullptr) return;
  const float* g = set ? gB : gA;
  const float* b = set ? bB : bA;
  double mean = sums[set * 128 + ch] / (double)N;
  double var = sums[set * 128 + 64 + ch] / (double)N - mean * mean;
  double inv = 1.0 / sqrt(var + (double)BN_EPS);
  float sc = (float)((double)g[ch] * inv);
  scales[set * 128 + ch] = sc;
  scales[set * 128 + 64 + ch] = b[ch] - (float)mean * sc;
}

// ---------------- h1pre -> elu(bn1(h1pre)) in place (bf16, gemm2's A tail) + fp8 copy
// h8 [N][64] (layer-2 gather table: 6.4 MB). 2 channels/thread.
__global__ __launch_bounds__(256) void bn_elu_inplace(u16* __restrict__ h,
                                                      u16* __restrict__ h8,
                                                      const float* __restrict__ sc,
                                                      int total2) {
  int idx = blockIdx.x * 256 + threadIdx.x;
  if (idx >= total2) return;
  int ch = (idx * 2) & 63;
  uint32 u = ((const uint32*)h)[idx];
  float v0 = __uint_as_float(u << 16);
  float v1 = __uint_as_float(u & 0xFFFF0000u);
  v0 = v0 * sc[ch] + sc[64 + ch];
  v1 = v1 * sc[ch + 1] + sc[64 + ch + 1];
  v0 = v0 > 0.f ? v0 : expm1f(v0);
  v1 = v1 > 0.f ? v1 : expm1f(v1);
  ((uint32*)h)[idx] = ((uint32)f2bf(v1) << 16) | (uint32)f2bf(v0);
  int p8 = __builtin_amdgcn_cvt_pk_fp8_f32(v0, v1, 0, false);  // byte0=v0, byte1=v1
  h8[idx] = (u16)(p8 & 0xFFFF);
}

// ---------------- epilogue: out = elu(bn2(h2pre) + bnS(skip)) ----------------
__global__ __launch_bounds__(256) void final_k(const u16* __restrict__ h2pre,
                                               const u16* __restrict__ skip,
                                               const float* __restrict__ sc2,
                                               const float* __restrict__ scS,
                                               float* __restrict__ out, int total) {
  int idx = blockIdx.x * 256 + threadIdx.x;
  if (idx >= total) return;
  int ch = idx & 63;
  float h2 = bf2f(h2pre[idx]) * sc2[ch] + sc2[64 + ch];
  float s = bf2f(skip[idx]) * scS[ch] + scS[64 + ch];
  float v = h2 + s;
  out[idx] = v > 0.f ? v : expm1f(v);
}

extern "C" void kernel_launch(void* const* d_in, const int* in_sizes, int n_in,
                              void* d_out, int out_size, void* d_ws, size_t ws_size,
                              hipStream_t stream) {
  const float* x     = (const float*)d_in[0];
  const int*   ei    = (const int*)d_in[1];
  const float* attr  = (const float*)d_in[2];
  const float* W1    = (const float*)d_in[3];
  const float* root1 = (const float*)d_in[4];
  const float* g1    = (const float*)d_in[5];
  const float* b1    = (const float*)d_in[6];
  const float* W2    = (const float*)d_in[7];
  const float* root2 = (const float*)d_in[8];
  const float* g2    = (const float*)d_in[9];
  const float* b2    = (const float*)d_in[10];
  const float* Wskip = (const float*)d_in[11];
  const float* gS    = (const float*)d_in[12];
  const float* bS    = (const float*)d_in[13];
  const int N = in_sizes[0] / 32;
  const int E = in_sizes[1] / 2;
  const int Nh = (N + 1) / 2;
  float* out = (float*)d_out;

  char* ws = (char*)d_ws;
  size_t off = 0;
  auto alloc = [&](size_t bytes) {
    void* p = ws + off;
    off = (off + bytes + 255) & ~(size_t)255;
    return p;
  };
  u16* B1t = (u16*)alloc(128 * 288 * 2);
  u16* B2t = (u16*)alloc(64 * 576 * 2);
  double* sums = (double*)alloc(6 * 64 * 8);    // [h1 | skip | h2] x {sum, sumsq}
  float* scales = (float*)alloc(6 * 64 * 4);    // [bn1 | bnS | bn2] x {scale, shift}
  int* indeg = (int*)alloc((size_t)N * 4);
  int* rowptr = (int*)alloc(((size_t)N + 1) * 4);
  int* part = (int*)alloc((size_t)N * 4);
  int* bsum = (int*)alloc(1024 * 4);
  int* rank = (int*)alloc((size_t)E * 4);                  // per-edge rank within dst
  uint4* emeta = (uint4*)alloc((size_t)E * 16);            // {src, fp16 u0|u1, fp16 u2, pad}
  u16* xbf = (u16*)alloc((size_t)N * 32 * 2);              // bf16 x (GEMM1 A-tail)
  uint32* x8 = (uint32*)alloc((size_t)N * 32);             // fp8 x (layer-1 gather, 3.2 MB)
  u16* h8 = (u16*)alloc((size_t)N * 64);                   // fp8 h1 (layer-2 gather table)
  u16* T = (u16*)alloc((size_t)(N + 2) * 256 * 2);         // T1 full [N][256] / T2 chunk [Nh][512]
  u16* h1 = (u16*)alloc((size_t)N * 64 * 2);               // h1pre -> elu(bn1()) in place
  u16* skip = (u16*)alloc((size_t)N * 64 * 2);             // x@Wskip (pre-BN)
  u16* h2 = (u16*)alloc((size_t)N * 64 * 2);               // h2pre
  if (off > ws_size) return;  // workspace too small: fail gracefully

  hipMemsetAsync(indeg, 0, (size_t)N * 4, stream);
  hipMemsetAsync(sums, 0, 6 * 64 * 8, stream);

  const int eblocks = (E + 255) / 256;
  const int nb = (N + 1023) / 1024;
  prep<<<(N * 4 + 255) / 256, 256, 0, stream>>>(W1, root1, Wskip, W2, root2, B1t, B2t,
                                                x, xbf, x8, N * 4);
  hist_dst<<<eblocks, 256, 0, stream>>>(ei, E, indeg, rank);
  scan_block<<<nb, 1024, 0, stream>>>(indeg, part, bsum, N);
  scan_top<<<1, 1024, 0, stream>>>(bsum, nb);
  scan_add<<<(N + 255) / 256, 256, 0, stream>>>(part, bsum, rowptr, N, E);
  edge_scatter<<<eblocks, 256, 0, stream>>>(ei, attr, rowptr, rank, E, emeta);

  // ---- layer 1: T1 = basis-weighted fp8-x aggregation; h1/skip = [T1 | xbf] @ B1t
  msg_accum<2, true><<<2048, 256, 0, stream>>>(x8, rowptr, (const u32x4*)emeta, 0, N, T);
  gemm_agg<256, 32, 128><<<(N + 63) / 64, 256, 0, stream>>>(T, xbf, B1t, h1, skip, 0, N,
                                                            sums);
  bn_finalize2<<<1, 128, 0, stream>>>(sums, g1, b1, gS, bS, scales, N);  // bn1 + bnS
  bn_elu_inplace<<<(N * 32 + 255) / 256, 256, 0, stream>>>(h1, h8, scales, N * 32);

  // ---- layer 2 in two row-chunks (T2 chunk buffer = 51.2 MB); gathers fp8 h8 ----
  for (int cph = 0; cph < 2; cph++) {
    int r0 = cph ? Nh : 0;
    int r1 = cph ? N : Nh;
    msg_accum<4, true><<<2048, 256, 0, stream>>>(h8, rowptr, (const u32x4*)emeta, r0, r1, T);
    gemm_agg<512, 64, 64><<<(r1 - r0 + 63) / 64, 256, 0, stream>>>(T, h1, B2t, h2, nullptr,
                                                                   r0, r1 - r0,
                                                                   sums + 4 * 64);
  }
  bn_finalize2<<<1, 64, 0, stream>>>(sums + 4 * 64, g2, b2, nullptr, nullptr,
                                     scales + 4 * 64, N);

  final_k<<<(N * 64 + 255) / 256, 256, 0, stream>>>(h2, skip, scales + 4 * 64,
                                                    scales + 2 * 64, out, N * 64);
}

// Round 12
// 568.214 us; speedup vs baseline: 1.0069x; 1.0031x over previous
//
#include <hip/hip_runtime.h>
#include <cstdint>

#define BN_EPS 1e-5f

typedef __attribute__((ext_vector_type(8))) short bf16x8;
typedef __attribute__((ext_vector_type(4))) float f32x4;
typedef __attribute__((ext_vector_type(2))) float f32x2;
typedef __attribute__((ext_vector_type(4))) unsigned int u32x4;
typedef unsigned int uint32;
typedef unsigned short u16;

__device__ inline u16 f2bf(float f) {
  unsigned int b = __float_as_uint(f);
  b += 0x7FFFu + ((b >> 16) & 1u);  // RNE
  return (u16)(b >> 16);
}
__device__ inline float bf2f(u16 u) { return __uint_as_float((unsigned int)u << 16); }

// ---------------- prep: pack weights + x->bf16 + x->fp8, one launch ----------------
// B1t [128 cols][288], B2t [64 cols][576] (bf16, row = out col).
// A-col index a: a<KT -> (i=a>>3, k=a&7) T-part (W[k,i,o]); a>=KT -> root/skip part.
// x8 [N][32] fp8 = 3.2 MB gather table (fits a 4 MiB per-XCD L2; bf16 xbf did not).
__global__ __launch_bounds__(256) void prep(const float* __restrict__ W1,
                                            const float* __restrict__ root1,
                                            const float* __restrict__ Wskip,
                                            const float* __restrict__ W2,
                                            const float* __restrict__ root2,
                                            u16* __restrict__ B1t, u16* __restrict__ B2t,
                                            const float* __restrict__ x,
                                            u16* __restrict__ xbf, uint32* __restrict__ x8,
                                            int total8) {
  int idx = blockIdx.x * 256 + threadIdx.x;
  if (idx < 128 * 288) {
    int n = idx / 288, a = idx % 288;
    float v;
    if (a < 256) {
      int i = a >> 3, k = a & 7;
      v = (n < 64) ? W1[k * 2048 + i * 64 + n] : 0.f;  // skip cols don't see T
    } else {
      int i = a - 256;
      v = (n < 64) ? root1[i * 64 + n] : Wskip[i * 64 + (n - 64)];
    }
    B1t[idx] = f2bf(v);
  } else if (idx < 128 * 288 + 64 * 576) {
    int j = idx - 128 * 288;
    int n = j / 576, a = j % 576;
    float v;
    if (a < 512) {
      int i = a >> 3, k = a & 7;
      v = W2[k * 4096 + i * 64 + n];
    } else {
      v = root2[(a - 512) * 64 + n];
    }
    B2t[j] = f2bf(v);
  }
  if (idx < total8) {
    const float4* xp = (const float4*)x;
    float4 a = xp[2 * idx], b = xp[2 * idx + 1];
    union { u16 s[8]; uint4 u; } p;
    p.s[0] = f2bf(a.x); p.s[1] = f2bf(a.y); p.s[2] = f2bf(a.z); p.s[3] = f2bf(a.w);
    p.s[4] = f2bf(b.x); p.s[5] = f2bf(b.y); p.s[6] = f2bf(b.z); p.s[7] = f2bf(b.w);
    ((uint4*)xbf)[idx] = p.u;
    uint32 w0 = (uint32)__builtin_amdgcn_cvt_pk_fp8_f32(a.x, a.y, 0, false);
    w0 = (uint32)__builtin_amdgcn_cvt_pk_fp8_f32(a.z, a.w, (int)w0, true);
    uint32 w1 = (uint32)__builtin_amdgcn_cvt_pk_fp8_f32(b.x, b.y, 0, false);
    w1 = (uint32)__builtin_amdgcn_cvt_pk_fp8_f32(b.z, b.w, (int)w1, true);
    x8[2 * idx + 0] = w0;
    x8[2 * idx + 1] = w1;
  }
}

// ---------------- dst-CSR build ----------------
// hist also records each edge's arrival rank within its dst segment: the atomic's
// return value. edge_scatter then needs NO atomic (pos = rowptr[dst] + rank[e]).
__global__ void hist_dst(const int* __restrict__ ei, int E, int* __restrict__ indeg,
                         int* __restrict__ rank) {
  int e = blockIdx.x * 256 + threadIdx.x;
  if (e >= E) return;
  rank[e] = atomicAdd(&indeg[ei[E + e]], 1);
}

__global__ __launch_bounds__(1024) void scan_block(const int* __restrict__ in,
                                                   int* __restrict__ part,
                                                   int* __restrict__ bsum, int N) {
  __shared__ int tmp[1024];
  int i = blockIdx.x * 1024 + threadIdx.x;
  int v = (i < N) ? in[i] : 0;
  tmp[threadIdx.x] = v;
  __syncthreads();
  for (int ofs = 1; ofs < 1024; ofs <<= 1) {
    int t = (threadIdx.x >= (unsigned)ofs) ? tmp[threadIdx.x - ofs] : 0;
    __syncthreads();
    tmp[threadIdx.x] += t;
    __syncthreads();
  }
  if (i < N) part[i] = tmp[threadIdx.x] - v;
  if (threadIdx.x == 1023) bsum[blockIdx.x] = tmp[1023];
}

__global__ __launch_bounds__(1024) void scan_top(int* __restrict__ bsum, int nb) {
  __shared__ int tmp[1024];
  int v = (threadIdx.x < (unsigned)nb) ? bsum[threadIdx.x] : 0;
  tmp[threadIdx.x] = v;
  __syncthreads();
  for (int ofs = 1; ofs < 1024; ofs <<= 1) {
    int t = (threadIdx.x >= (unsigned)ofs) ? tmp[threadIdx.x - ofs] : 0;
    __syncthreads();
    tmp[threadIdx.x] += t;
    __syncthreads();
  }
  if (threadIdx.x < (unsigned)nb) bsum[threadIdx.x] = tmp[threadIdx.x] - v;
}

__global__ void scan_add(const int* __restrict__ part, const int* __restrict__ bsum,
                         int* __restrict__ rowptr, int N, int E) {
  int i = blockIdx.x * 256 + threadIdx.x;
  if (i < N) rowptr[i] = part[i] + bsum[i >> 10];
  if (i == 0) rowptr[N] = E;
}

// Scatter: ONE 16-B record per edge: {src, fp16 u0|u1, fp16 u2|0, pad}.
// Position = rowptr[dst] + rank[e] (no atomic -> stores issue in bursts; partner
// quarter-lines co-reside in L2/L3 and merge: measured WRITE ~= payload).
// NOTE: keep these stores NORMAL (cached) — nt would break the L2 merging.
__global__ __launch_bounds__(256) void edge_scatter(const int* __restrict__ ei,
                                                    const float* __restrict__ attr,
                                                    const int* __restrict__ rowptr,
                                                    const int* __restrict__ rank, int E,
                                                    uint4* __restrict__ emeta) {
  int e = blockIdx.x * 256 + threadIdx.x;
  if (e >= E) return;
  int src = ei[e], dst = ei[E + e];
  union { _Float16 h[2]; uint32 u; } y, z;
  y.h[0] = (_Float16)attr[3 * e + 0];
  y.h[1] = (_Float16)attr[3 * e + 1];
  z.h[0] = (_Float16)attr[3 * e + 2];
  z.h[1] = (_Float16)0.f;
  int pos = rowptr[dst] + rank[e];
  emeta[pos] = make_uint4((uint32)src, y.u, z.u, 0u);
}

// ---------------- basis-first aggregation: T[dst][ch*8+k] = (1/deg) * sum_e w_k * tab[src][ch]
// 16 lanes per edge (p = lane&15), 4 edge-groups per wave (eh = lane>>4).
// PC channels per lane: layer1 PC=2 fp8 [N][32] (3.2 MB, L2-fit), layer2 PC=4 fp8 [N][64].
// emeta loads NON-TEMPORAL (read-once stream; protects the table's L2 residency).
// T stores NORMAL (nt T-stores doubled WRITE and evicted T before gemm read it - r10).
// Inner-loop math is PACKED f32x2 (v_pk_fma_f32): cvt_pk_f32_fp8 already produces f32x2
// pairs, so the FMA count halves (msg was VALU-bound: 63% VALUBusy, 17% HBM).
template <int PC, bool F8>
__device__ inline void sc_gather(const void* __restrict__ tab, int src, int p,
                                 f32x2* __restrict__ xf) {
  if (F8 && PC == 4) {
    // 4 fp8 channels at byte offset 4p of a 64-B row
    uint32 u = *(const uint32*)((const char*)tab + (size_t)src * 64 + 4 * p);
    xf[0] = __builtin_amdgcn_cvt_pk_f32_fp8((int)u, false);
    xf[1] = __builtin_amdgcn_cvt_pk_f32_fp8((int)u, true);
  } else if (F8 && PC == 2) {
    // 2 fp8 channels at byte offset 2p of a 32-B row
    u16 us = *(const u16*)((const char*)tab + (size_t)src * 32 + 2 * p);
    xf[0] = __builtin_amdgcn_cvt_pk_f32_fp8((int)us, false);
  } else {
    // 2 bf16 channels at channel 2p of a 32-ch row
    uint32 u = *(const uint32*)((const u16*)tab + (size_t)src * 32 + 2 * p);
    xf[0] = f32x2{__uint_as_float(u << 16), __uint_as_float(u & 0xFFFF0000u)};
  }
}

// Recompute the 8 trilinear basis weights from the packed fp16 attrs, then packed FMA.
template <int PC>
__device__ inline void sc_fma(f32x2* __restrict__ acc2, u32x4 m,
                              const f32x2* __restrict__ xf) {
  union { uint32 u; _Float16 h[2]; } cy, cz;
  cy.u = m.y;
  cz.u = m.z;
  float u0 = (float)cy.h[0], u1 = (float)cy.h[1], u2 = (float)cz.h[0];
  float p0 = 1.f - u0, p1 = 1.f - u1, p2 = 1.f - u2;
  float w00 = p1 * p2, w10 = u1 * p2, w01 = p1 * u2, w11 = u1 * u2;
  float w[8] = {p0 * w00, u0 * w00, p0 * w10, u0 * w10,
                p0 * w01, u0 * w01, p0 * w11, u0 * w11};
#pragma unroll
  for (int k = 0; k < 8; k++) {
#pragma unroll
    for (int h = 0; h < PC / 2; h++) acc2[k * (PC / 2) + h] += xf[h] * w[k];
  }
}

template <int PC, bool F8>
__global__ __launch_bounds__(256) void msg_accum(const void* __restrict__ tab,
                                                 const int* __restrict__ rowptr,
                                                 const u32x4* __restrict__ emeta,
                                                 int n0, int n1, u16* __restrict__ T) {
  const int tid = threadIdx.x;
  const int lane = tid & 63;
  const int wv = tid >> 6;
  const int nwaves = gridDim.x * 4;
  const int p = lane & 15;
  const int eh = lane >> 4;  // 0..3
  const int PCH = PC / 2;

  for (int n = n0 + blockIdx.x * 4 + wv; n < n1; n += nwaves) {
    const int e0 = __builtin_amdgcn_readfirstlane(rowptr[n]);
    const int e1 = __builtin_amdgcn_readfirstlane(rowptr[n + 1]);
    f32x2 acc2[4 * PC];  // [k][c-pair], 8*PC floats
#pragma unroll
    for (int j = 0; j < 4 * PC; j++) acc2[j] = f32x2{0.f, 0.f};

    int e = e0;
    // 8 edges per iteration: 4 groups x 2 pairs -> 2 meta loads + 2 gathers in flight.
    for (; e + 8 <= e1; e += 8) {
      u32x4 a = __builtin_nontemporal_load(&emeta[e + eh]);
      u32x4 b = __builtin_nontemporal_load(&emeta[e + 4 + eh]);
      f32x2 xa[PC / 2], xb[PC / 2];
      sc_gather<PC, F8>(tab, (int)a.x, p, xa);
      sc_gather<PC, F8>(tab, (int)b.x, p, xb);
      sc_fma<PC>(acc2, a, xa);
      sc_fma<PC>(acc2, b, xb);
    }
    // tail: <=7 edges, masked quads
    for (; e < e1; e += 4) {
      int ee = e + eh;
      bool act = ee < e1;
      if (!act) ee = e;
      u32x4 m = __builtin_nontemporal_load(&emeta[ee]);
      f32x2 xv[PC / 2];
      sc_gather<PC, F8>(tab, (int)m.x, p, xv);
      if (!act) {
#pragma unroll
        for (int h = 0; h < PC / 2; h++) xv[h] = f32x2{0.f, 0.f};
      }
      sc_fma<PC>(acc2, m, xv);
    }

    // reduce across the 4 edge-groups (per component)
#pragma unroll
    for (int j = 0; j < 4 * PC; j++) {
      f32x2 v = acc2[j];
      v.x += __shfl_xor(v.x, 16);
      v.x += __shfl_xor(v.x, 32);
      v.y += __shfl_xor(v.y, 16);
      v.y += __shfl_xor(v.y, 32);
      acc2[j] = v;
    }

    float inv = 1.f / fmaxf((float)(e1 - e0), 1.f);
    if (eh == 0) {
      u16* rowp = T + (size_t)(n - n0) * (128 * PC);
#pragma unroll
      for (int c = 0; c < PC; c++) {
        union { u16 s[8]; uint4 u; } pk;
#pragma unroll
        for (int k = 0; k < 8; k++) {
          f32x2 v = acc2[k * PCH + (c >> 1)];
          pk.s[k] = f2bf(((c & 1) ? v.y : v.x) * inv);
        }
        *(uint4*)(rowp + ((size_t)(PC * p + c)) * 8) = pk.u;
      }
    }
  }
}

// ---------------- MFMA GEMM: out = [T | X] @ Bt^T, A all-bf16, output bf16 split at col 64.
// __launch_bounds__(256,3); afrag preloaded once into registers (normal loads: T is
// L2-warm from msg_accum's cached stores). Bt staged in LDS in two column halves
// (ds_read_b128 instead of ~200-cyc L2 hits). BN stats via LDS + double atomics.
template <int KT, int KX, int NC>
__global__ __launch_bounds__(256, 3) void gemm_agg(const u16* __restrict__ T,
                                                   const u16* __restrict__ X,
                                                   const u16* __restrict__ Bt,
                                                   u16* __restrict__ O1, u16* __restrict__ O2,
                                                   int rowOff, int rows,
                                                   double* __restrict__ sums) {
  const int K = KT + KX;
  const int KP = K + 8;     // padded LDS row stride (u16 units)
  const int NCH = NC / 2;   // staged columns per half
  const int tid = threadIdx.x;
  const int lane = tid & 63;
  const int wv = tid >> 6;
  const int rowbase = blockIdx.x * 64 + wv * 16;
  const int m = lane & 15;
  const int quad = lane >> 4;
  const int k0 = quad * 8;

  __shared__ u16 bs[NCH * (KT + KX + 8)];
  __shared__ float slds[4][NC][2];

  int ar = rowbase + m;
  if (ar > rows - 1) ar = rows - 1;

  bf16x8 afrag[K / 32];
#pragma unroll
  for (int f = 0; f < K / 32; f++) {
    if (f * 32 < KT)
      afrag[f] = *(const bf16x8*)(T + (size_t)ar * KT + f * 32 + k0);
    else
      afrag[f] = *(const bf16x8*)(X + (size_t)(rowOff + ar) * KX + (f * 32 - KT) + k0);
  }

  for (int halfc = 0; halfc < 2; halfc++) {
    __syncthreads();  // prior-half readers done before overwrite (no-op cost on 1st)
    for (int i = tid; i < NCH * (K / 8); i += 256) {
      int col = i / (K / 8);
      int kk = (i % (K / 8)) * 8;
      *(uint4*)(bs + col * KP + kk) =
          *(const uint4*)(Bt + (size_t)(halfc * NCH + col) * K + kk);
    }
    __syncthreads();

    for (int col0 = 0; col0 < NCH; col0 += 32) {
      f32x4 acc0 = {0.f, 0.f, 0.f, 0.f};
      f32x4 acc1 = {0.f, 0.f, 0.f, 0.f};
#pragma unroll
      for (int f = 0; f < K / 32; f++) {
        bf16x8 b0 = *(const bf16x8*)(bs + (col0 + m) * KP + f * 32 + k0);
        bf16x8 b1 = *(const bf16x8*)(bs + (col0 + 16 + m) * KP + f * 32 + k0);
        acc0 = __builtin_amdgcn_mfma_f32_16x16x32_bf16(afrag[f], b0, acc0, 0, 0, 0);
        acc1 = __builtin_amdgcn_mfma_f32_16x16x32_bf16(afrag[f], b1, acc1, 0, 0, 0);
      }
#pragma unroll
      for (int half = 0; half < 2; half++) {
        const f32x4& acc = half ? acc1 : acc0;
        const int col = halfc * NCH + col0 + half * 16 + m;
        float s1 = 0.f, s2 = 0.f;
#pragma unroll
        for (int r = 0; r < 4; r++) {
          int gr = rowbase + quad * 4 + r;
          if (gr < rows) {
            size_t g = (size_t)(rowOff + gr);
            u16 vq = f2bf(acc[r]);
            float v = bf2f(vq);
            s1 += v;
            s2 += v * v;
            if (NC == 64 || col < 64) O1[g * 64 + col] = vq;
            else O2[g * 64 + (col - 64)] = vq;
          }
        }
        // reduce the 64 block-rows for this col: quads live at lane m+16q
        s1 += __shfl_xor(s1, 16); s1 += __shfl_xor(s1, 32);
        s2 += __shfl_xor(s2, 16); s2 += __shfl_xor(s2, 32);
        if (lane < 16) { slds[wv][col][0] = s1; slds[wv][col][1] = s2; }
      }
    }
  }
  __syncthreads();
  if (tid < NC * 2) {
    int col = tid >> 1, which = tid & 1;
    float v = slds[0][col][which] + slds[1][col][which] + slds[2][col][which] +
              slds[3][col][which];
    int slot = ((NC > 64 && col >= 64) ? 128 : 0) + which * 64 + (col & 63);
    atomicAdd(&sums[slot], (double)v);
  }
}

// ---------------- bn finalize: one or two parameter sets per launch ----------------
__global__ void bn_finalize2(const double* __restrict__ sums, const float* __restrict__ gA,
                             const float* __restrict__ bA, const float* __restrict__ gB,
                             const float* __restrict__ bB, float* __restrict__ scales, int N) {
  int t = threadIdx.x;
  int set = t >> 6, ch = t & 63;
  if (set == 1 && gB == nullptr) return;
  const float* g = set ? gB : gA;
  const float* b = set ? bB : bA;
  double mean = sums[set * 128 + ch] / (double)N;
  double var = sums[set * 128 + 64 + ch] / (double)N - mean * mean;
  double inv = 1.0 / sqrt(var + (double)BN_EPS);
  float sc = (float)((double)g[ch] * inv);
  scales[set * 128 + ch] = sc;
  scales[set * 128 + 64 + ch] = b[ch] - (float)mean * sc;
}

// ---------------- h1pre -> elu(bn1(h1pre)) in place (bf16, gemm2's A tail) + fp8 copy
// h8 [N][64] (layer-2 gather table: 6.4 MB). 2 channels/thread.
__global__ __launch_bounds__(256) void bn_elu_inplace(u16* __restrict__ h,
                                                      u16* __restrict__ h8,
                                                      const float* __restrict__ sc,
                                                      int total2) {
  int idx = blockIdx.x * 256 + threadIdx.x;
  if (idx >= total2) return;
  int ch = (idx * 2) & 63;
  uint32 u = ((const uint32*)h)[idx];
  float v0 = __uint_as_float(u << 16);
  float v1 = __uint_as_float(u & 0xFFFF0000u);
  v0 = v0 * sc[ch] + sc[64 + ch];
  v1 = v1 * sc[ch + 1] + sc[64 + ch + 1];
  v0 = v0 > 0.f ? v0 : expm1f(v0);
  v1 = v1 > 0.f ? v1 : expm1f(v1);
  ((uint32*)h)[idx] = ((uint32)f2bf(v1) << 16) | (uint32)f2bf(v0);
  int p8 = __builtin_amdgcn_cvt_pk_fp8_f32(v0, v1, 0, false);  // byte0=v0, byte1=v1
  h8[idx] = (u16)(p8 & 0xFFFF);
}

// ---------------- epilogue: out = elu(bn2(h2pre) + bnS(skip)) ----------------
__global__ __launch_bounds__(256) void final_k(const u16* __restrict__ h2pre,
                                               const u16* __restrict__ skip,
                                               const float* __restrict__ sc2,
                                               const float* __restrict__ scS,
                                               float* __restrict__ out, int total) {
  int idx = blockIdx.x * 256 + threadIdx.x;
  if (idx >= total) return;
  int ch = idx & 63;
  float h2 = bf2f(h2pre[idx]) * sc2[ch] + sc2[64 + ch];
  float s = bf2f(skip[idx]) * scS[ch] + scS[64 + ch];
  float v = h2 + s;
  out[idx] = v > 0.f ? v : expm1f(v);
}

extern "C" void kernel_launch(void* const* d_in, const int* in_sizes, int n_in,
                              void* d_out, int out_size, void* d_ws, size_t ws_size,
                              hipStream_t stream) {
  const float* x     = (const float*)d_in[0];
  const int*   ei    = (const int*)d_in[1];
  const float* attr  = (const float*)d_in[2];
  const float* W1    = (const float*)d_in[3];
  const float* root1 = (const float*)d_in[4];
  const float* g1    = (const float*)d_in[5];
  const float* b1    = (const float*)d_in[6];
  const float* W2    = (const float*)d_in[7];
  const float* root2 = (const float*)d_in[8];
  const float* g2    = (const float*)d_in[9];
  const float* b2    = (const float*)d_in[10];
  const float* Wskip = (const float*)d_in[11];
  const float* gS    = (const float*)d_in[12];
  const float* bS    = (const float*)d_in[13];
  const int N = in_sizes[0] / 32;
  const int E = in_sizes[1] / 2;
  const int Nh = (N + 1) / 2;
  float* out = (float*)d_out;

  char* ws = (char*)d_ws;
  size_t off = 0;
  auto alloc = [&](size_t bytes) {
    void* p = ws + off;
    off = (off + bytes + 255) & ~(size_t)255;
    return p;
  };
  u16* B1t = (u16*)alloc(128 * 288 * 2);
  u16* B2t = (u16*)alloc(64 * 576 * 2);
  double* sums = (double*)alloc(6 * 64 * 8);    // [h1 | skip | h2] x {sum, sumsq}
  float* scales = (float*)alloc(6 * 64 * 4);    // [bn1 | bnS | bn2] x {scale, shift}
  int* indeg = (int*)alloc((size_t)N * 4);
  int* rowptr = (int*)alloc(((size_t)N + 1) * 4);
  int* part = (int*)alloc((size_t)N * 4);
  int* bsum = (int*)alloc(1024 * 4);
  int* rank = (int*)alloc((size_t)E * 4);                  // per-edge rank within dst
  uint4* emeta = (uint4*)alloc((size_t)E * 16);            // {src, fp16 u0|u1, fp16 u2, pad}
  u16* xbf = (u16*)alloc((size_t)N * 32 * 2);              // bf16 x (GEMM1 A-tail)
  uint32* x8 = (uint32*)alloc((size_t)N * 32);             // fp8 x (layer-1 gather, 3.2 MB)
  u16* h8 = (u16*)alloc((size_t)N * 64);                   // fp8 h1 (layer-2 gather table)
  u16* T = (u16*)alloc((size_t)(N + 2) * 256 * 2);         // T1 full [N][256] / T2 chunk [Nh][512]
  u16* h1 = (u16*)alloc((size_t)N * 64 * 2);               // h1pre -> elu(bn1()) in place
  u16* skip = (u16*)alloc((size_t)N * 64 * 2);             // x@Wskip (pre-BN)
  u16* h2 = (u16*)alloc((size_t)N * 64 * 2);               // h2pre
  if (off > ws_size) return;  // workspace too small: fail gracefully

  hipMemsetAsync(indeg, 0, (size_t)N * 4, stream);
  hipMemsetAsync(sums, 0, 6 * 64 * 8, stream);

  const int eblocks = (E + 255) / 256;
  const int nb = (N + 1023) / 1024;
  prep<<<(N * 4 + 255) / 256, 256, 0, stream>>>(W1, root1, Wskip, W2, root2, B1t, B2t,
                                                x, xbf, x8, N * 4);
  hist_dst<<<eblocks, 256, 0, stream>>>(ei, E, indeg, rank);
  scan_block<<<nb, 1024, 0, stream>>>(indeg, part, bsum, N);
  scan_top<<<1, 1024, 0, stream>>>(bsum, nb);
  scan_add<<<(N + 255) / 256, 256, 0, stream>>>(part, bsum, rowptr, N, E);
  edge_scatter<<<eblocks, 256, 0, stream>>>(ei, attr, rowptr, rank, E, emeta);

  // ---- layer 1: T1 = basis-weighted fp8-x aggregation; h1/skip = [T1 | xbf] @ B1t
  msg_accum<2, true><<<2048, 256, 0, stream>>>(x8, rowptr, (const u32x4*)emeta, 0, N, T);
  gemm_agg<256, 32, 128><<<(N + 63) / 64, 256, 0, stream>>>(T, xbf, B1t, h1, skip, 0, N,
                                                            sums);
  bn_finalize2<<<1, 128, 0, stream>>>(sums, g1, b1, gS, bS, scales, N);  // bn1 + bnS
  bn_elu_inplace<<<(N * 32 + 255) / 256, 256, 0, stream>>>(h1, h8, scales, N * 32);

  // ---- layer 2 in two row-chunks (T2 chunk buffer = 51.2 MB); gathers fp8 h8 ----
  for (int cph = 0; cph < 2; cph++) {
    int r0 = cph ? Nh : 0;
    int r1 = cph ? N : Nh;
    msg_accum<4, true><<<2048, 256, 0, stream>>>(h8, rowptr, (const u32x4*)emeta, r0, r1, T);
    gemm_agg<512, 64, 64><<<(r1 - r0 + 63) / 64, 256, 0, stream>>>(T, h1, B2t, h2, nullptr,
                                                                   r0, r1 - r0,
                                                                   sums + 4 * 64);
  }
  bn_finalize2<<<1, 64, 0, stream>>>(sums + 4 * 64, g2, b2, nullptr, nullptr,
                                     scales + 4 * 64, N);

  final_k<<<(N * 64 + 255) / 256, 256, 0, stream>>>(h2, skip, scales + 4 * 64,
                                                    scales + 2 * 64, out, N * 64);
}

// Round 13
// 547.892 us; speedup vs baseline: 1.0443x; 1.0371x over previous
//
#include <hip/hip_runtime.h>
#include <cstdint>

#define BN_EPS 1e-5f

typedef __attribute__((ext_vector_type(8))) short bf16x8;
typedef __attribute__((ext_vector_type(4))) float f32x4;
typedef __attribute__((ext_vector_type(2))) float f32x2;
typedef __attribute__((ext_vector_type(4))) unsigned int u32x4;
typedef unsigned int uint32;
typedef unsigned short u16;

__device__ inline u16 f2bf(float f) {
  unsigned int b = __float_as_uint(f);
  b += 0x7FFFu + ((b >> 16) & 1u);  // RNE
  return (u16)(b >> 16);
}
__device__ inline float bf2f(u16 u) { return __uint_as_float((unsigned int)u << 16); }

// ---------------- prep: pack weights + x->bf16 + x->fp8, one launch ----------------
// B1t [128 cols][288], B2t [64 cols][576] (bf16, row = out col).
// A-col index a: a<KT -> (i=a>>3, k=a&7) T-part (W[k,i,o]); a>=KT -> root/skip part.
// x8 [N][32] fp8 = 3.2 MB gather table (fits a 4 MiB per-XCD L2; bf16 xbf did not).
__global__ __launch_bounds__(256) void prep(const float* __restrict__ W1,
                                            const float* __restrict__ root1,
                                            const float* __restrict__ Wskip,
                                            const float* __restrict__ W2,
                                            const float* __restrict__ root2,
                                            u16* __restrict__ B1t, u16* __restrict__ B2t,
                                            const float* __restrict__ x,
                                            u16* __restrict__ xbf, uint32* __restrict__ x8,
                                            int total8) {
  int idx = blockIdx.x * 256 + threadIdx.x;
  if (idx < 128 * 288) {
    int n = idx / 288, a = idx % 288;
    float v;
    if (a < 256) {
      int i = a >> 3, k = a & 7;
      v = (n < 64) ? W1[k * 2048 + i * 64 + n] : 0.f;  // skip cols don't see T
    } else {
      int i = a - 256;
      v = (n < 64) ? root1[i * 64 + n] : Wskip[i * 64 + (n - 64)];
    }
    B1t[idx] = f2bf(v);
  } else if (idx < 128 * 288 + 64 * 576) {
    int j = idx - 128 * 288;
    int n = j / 576, a = j % 576;
    float v;
    if (a < 512) {
      int i = a >> 3, k = a & 7;
      v = W2[k * 4096 + i * 64 + n];
    } else {
      v = root2[(a - 512) * 64 + n];
    }
    B2t[j] = f2bf(v);
  }
  if (idx < total8) {
    const float4* xp = (const float4*)x;
    float4 a = xp[2 * idx], b = xp[2 * idx + 1];
    union { u16 s[8]; uint4 u; } p;
    p.s[0] = f2bf(a.x); p.s[1] = f2bf(a.y); p.s[2] = f2bf(a.z); p.s[3] = f2bf(a.w);
    p.s[4] = f2bf(b.x); p.s[5] = f2bf(b.y); p.s[6] = f2bf(b.z); p.s[7] = f2bf(b.w);
    ((uint4*)xbf)[idx] = p.u;
    uint32 w0 = (uint32)__builtin_amdgcn_cvt_pk_fp8_f32(a.x, a.y, 0, false);
    w0 = (uint32)__builtin_amdgcn_cvt_pk_fp8_f32(a.z, a.w, (int)w0, true);
    uint32 w1 = (uint32)__builtin_amdgcn_cvt_pk_fp8_f32(b.x, b.y, 0, false);
    w1 = (uint32)__builtin_amdgcn_cvt_pk_fp8_f32(b.z, b.w, (int)w1, true);
    x8[2 * idx + 0] = w0;
    x8[2 * idx + 1] = w1;
  }
}

// ---------------- dst-CSR build ----------------
// hist also records each edge's arrival rank within its dst segment: the atomic's
// return value. edge_scatter then needs NO atomic (pos = rowptr[dst] + rank[e]).
__global__ void hist_dst(const int* __restrict__ ei, int E, int* __restrict__ indeg,
                         int* __restrict__ rank) {
  int e = blockIdx.x * 256 + threadIdx.x;
  if (e >= E) return;
  rank[e] = atomicAdd(&indeg[ei[E + e]], 1);
}

__global__ __launch_bounds__(1024) void scan_block(const int* __restrict__ in,
                                                   int* __restrict__ part,
                                                   int* __restrict__ bsum, int N) {
  __shared__ int tmp[1024];
  int i = blockIdx.x * 1024 + threadIdx.x;
  int v = (i < N) ? in[i] : 0;
  tmp[threadIdx.x] = v;
  __syncthreads();
  for (int ofs = 1; ofs < 1024; ofs <<= 1) {
    int t = (threadIdx.x >= (unsigned)ofs) ? tmp[threadIdx.x - ofs] : 0;
    __syncthreads();
    tmp[threadIdx.x] += t;
    __syncthreads();
  }
  if (i < N) part[i] = tmp[threadIdx.x] - v;
  if (threadIdx.x == 1023) bsum[blockIdx.x] = tmp[1023];
}

__global__ __launch_bounds__(1024) void scan_top(int* __restrict__ bsum, int nb) {
  __shared__ int tmp[1024];
  int v = (threadIdx.x < (unsigned)nb) ? bsum[threadIdx.x] : 0;
  tmp[threadIdx.x] = v;
  __syncthreads();
  for (int ofs = 1; ofs < 1024; ofs <<= 1) {
    int t = (threadIdx.x >= (unsigned)ofs) ? tmp[threadIdx.x - ofs] : 0;
    __syncthreads();
    tmp[threadIdx.x] += t;
    __syncthreads();
  }
  if (threadIdx.x < (unsigned)nb) bsum[threadIdx.x] = tmp[threadIdx.x] - v;
}

__global__ void scan_add(const int* __restrict__ part, const int* __restrict__ bsum,
                         int* __restrict__ rowptr, int N, int E) {
  int i = blockIdx.x * 256 + threadIdx.x;
  if (i < N) rowptr[i] = part[i] + bsum[i >> 10];
  if (i == 0) rowptr[N] = E;
}

// Scatter: ONE 16-B record per edge: {src, fp16 u0|u1, fp16 u2|0, pad}.
// Position = rowptr[dst] + rank[e] (no atomic -> stores issue in bursts; partner
// quarter-lines co-reside in L2/L3 and merge: measured WRITE ~= payload).
// NOTE: keep these stores NORMAL (cached) — nt would break the L2 merging.
__global__ __launch_bounds__(256) void edge_scatter(const int* __restrict__ ei,
                                                    const float* __restrict__ attr,
                                                    const int* __restrict__ rowptr,
                                                    const int* __restrict__ rank, int E,
                                                    uint4* __restrict__ emeta) {
  int e = blockIdx.x * 256 + threadIdx.x;
  if (e >= E) return;
  int src = ei[e], dst = ei[E + e];
  union { _Float16 h[2]; uint32 u; } y, z;
  y.h[0] = (_Float16)attr[3 * e + 0];
  y.h[1] = (_Float16)attr[3 * e + 1];
  z.h[0] = (_Float16)attr[3 * e + 2];
  z.h[1] = (_Float16)0.f;
  int pos = rowptr[dst] + rank[e];
  emeta[pos] = make_uint4((uint32)src, y.u, z.u, 0u);
}

// ---------------- basis-first aggregation: T[dst][ch*8+k] = (1/deg) * sum_e w_k * tab[src][ch]
// 16 lanes per edge (p = lane&15), 4 edge-groups per wave (eh = lane>>4).
// PC channels per lane: layer1 PC=2 fp8 [N][32] (3.2 MB, L2-fit), layer2 PC=4 fp8 [N][64].
// emeta loads are PLAIN (cached): round-12's nt loads were no-allocate, so all THREE msg
// passes re-fetched 25.6 MB of emeta from DRAM (FETCH 47 MB each). Plain loads let pass 1
// fill L3; passes 2-3 hit L3. T stores NORMAL (nt T-stores doubled WRITE in r10).
// Inner-loop math is PACKED f32x2 (cvt_pk_f32_fp8 produces pairs natively).
template <int PC, bool F8>
__device__ inline void sc_gather(const void* __restrict__ tab, int src, int p,
                                 f32x2* __restrict__ xf) {
  if (F8 && PC == 4) {
    // 4 fp8 channels at byte offset 4p of a 64-B row
    uint32 u = *(const uint32*)((const char*)tab + (size_t)src * 64 + 4 * p);
    xf[0] = __builtin_amdgcn_cvt_pk_f32_fp8((int)u, false);
    xf[1] = __builtin_amdgcn_cvt_pk_f32_fp8((int)u, true);
  } else if (F8 && PC == 2) {
    // 2 fp8 channels at byte offset 2p of a 32-B row
    u16 us = *(const u16*)((const char*)tab + (size_t)src * 32 + 2 * p);
    xf[0] = __builtin_amdgcn_cvt_pk_f32_fp8((int)us, false);
  } else {
    // 2 bf16 channels at channel 2p of a 32-ch row
    uint32 u = *(const uint32*)((const u16*)tab + (size_t)src * 32 + 2 * p);
    xf[0] = f32x2{__uint_as_float(u << 16), __uint_as_float(u & 0xFFFF0000u)};
  }
}

// Recompute the 8 trilinear basis weights from the packed fp16 attrs, then packed FMA.
template <int PC>
__device__ inline void sc_fma(f32x2* __restrict__ acc2, u32x4 m,
                              const f32x2* __restrict__ xf) {
  union { uint32 u; _Float16 h[2]; } cy, cz;
  cy.u = m.y;
  cz.u = m.z;
  float u0 = (float)cy.h[0], u1 = (float)cy.h[1], u2 = (float)cz.h[0];
  float p0 = 1.f - u0, p1 = 1.f - u1, p2 = 1.f - u2;
  float w00 = p1 * p2, w10 = u1 * p2, w01 = p1 * u2, w11 = u1 * u2;
  float w[8] = {p0 * w00, u0 * w00, p0 * w10, u0 * w10,
                p0 * w01, u0 * w01, p0 * w11, u0 * w11};
#pragma unroll
  for (int k = 0; k < 8; k++) {
#pragma unroll
    for (int h = 0; h < PC / 2; h++) acc2[k * (PC / 2) + h] += xf[h] * w[k];
  }
}

template <int PC, bool F8>
__global__ __launch_bounds__(256) void msg_accum(const void* __restrict__ tab,
                                                 const int* __restrict__ rowptr,
                                                 const u32x4* __restrict__ emeta,
                                                 int n0, int n1, u16* __restrict__ T) {
  const int tid = threadIdx.x;
  const int lane = tid & 63;
  const int wv = tid >> 6;
  const int nwaves = gridDim.x * 4;
  const int p = lane & 15;
  const int eh = lane >> 4;  // 0..3
  const int PCH = PC / 2;

  for (int n = n0 + blockIdx.x * 4 + wv; n < n1; n += nwaves) {
    const int e0 = __builtin_amdgcn_readfirstlane(rowptr[n]);
    const int e1 = __builtin_amdgcn_readfirstlane(rowptr[n + 1]);
    f32x2 acc2[4 * PC];  // [k][c-pair], 8*PC floats
#pragma unroll
    for (int j = 0; j < 4 * PC; j++) acc2[j] = f32x2{0.f, 0.f};

    int e = e0;
    // 8 edges per iteration: 4 groups x 2 pairs -> 2 meta loads + 2 gathers in flight.
    for (; e + 8 <= e1; e += 8) {
      u32x4 a = emeta[e + eh];
      u32x4 b = emeta[e + 4 + eh];
      f32x2 xa[PC / 2], xb[PC / 2];
      sc_gather<PC, F8>(tab, (int)a.x, p, xa);
      sc_gather<PC, F8>(tab, (int)b.x, p, xb);
      sc_fma<PC>(acc2, a, xa);
      sc_fma<PC>(acc2, b, xb);
    }
    // tail: <=7 edges, masked quads
    for (; e < e1; e += 4) {
      int ee = e + eh;
      bool act = ee < e1;
      if (!act) ee = e;
      u32x4 m = emeta[ee];
      f32x2 xv[PC / 2];
      sc_gather<PC, F8>(tab, (int)m.x, p, xv);
      if (!act) {
#pragma unroll
        for (int h = 0; h < PC / 2; h++) xv[h] = f32x2{0.f, 0.f};
      }
      sc_fma<PC>(acc2, m, xv);
    }

    // reduce across the 4 edge-groups (per component)
#pragma unroll
    for (int j = 0; j < 4 * PC; j++) {
      f32x2 v = acc2[j];
      v.x += __shfl_xor(v.x, 16);
      v.x += __shfl_xor(v.x, 32);
      v.y += __shfl_xor(v.y, 16);
      v.y += __shfl_xor(v.y, 32);
      acc2[j] = v;
    }

    float inv = 1.f / fmaxf((float)(e1 - e0), 1.f);
    if (eh == 0) {
      u16* rowp = T + (size_t)(n - n0) * (128 * PC);
#pragma unroll
      for (int c = 0; c < PC; c++) {
        union { u16 s[8]; uint4 u; } pk;
#pragma unroll
        for (int k = 0; k < 8; k++) {
          f32x2 v = acc2[k * PCH + (c >> 1)];
          pk.s[k] = f2bf(((c & 1) ? v.y : v.x) * inv);
        }
        *(uint4*)(rowp + ((size_t)(PC * p + c)) * 8) = pk.u;
      }
    }
  }
}

// ---------------- MFMA GEMM: out = [T | X] @ Bt^T, A all-bf16, output bf16 split at col 64.
// __launch_bounds__(256,MW): MW=4 for layer 1 (afrag only 36 VGPR at K=288 -> 128-VGPR
// budget fits, 4 blocks/CU hides latency), MW=3 for layer 2 (K=576 afrag = 72 VGPR).
// afrag preloaded once into registers (T is L2-warm from msg_accum's cached stores).
// Bt staged in LDS in two column halves. BN stats via LDS + double atomics.
template <int KT, int KX, int NC, int MW>
__global__ __launch_bounds__(256, MW) void gemm_agg(const u16* __restrict__ T,
                                                    const u16* __restrict__ X,
                                                    const u16* __restrict__ Bt,
                                                    u16* __restrict__ O1, u16* __restrict__ O2,
                                                    int rowOff, int rows,
                                                    double* __restrict__ sums) {
  const int K = KT + KX;
  const int KP = K + 8;     // padded LDS row stride (u16 units)
  const int NCH = NC / 2;   // staged columns per half
  const int tid = threadIdx.x;
  const int lane = tid & 63;
  const int wv = tid >> 6;
  const int rowbase = blockIdx.x * 64 + wv * 16;
  const int m = lane & 15;
  const int quad = lane >> 4;
  const int k0 = quad * 8;

  __shared__ u16 bs[NCH * (KT + KX + 8)];
  __shared__ float slds[4][NC][2];

  int ar = rowbase + m;
  if (ar > rows - 1) ar = rows - 1;

  bf16x8 afrag[K / 32];
#pragma unroll
  for (int f = 0; f < K / 32; f++) {
    if (f * 32 < KT)
      afrag[f] = *(const bf16x8*)(T + (size_t)ar * KT + f * 32 + k0);
    else
      afrag[f] = *(const bf16x8*)(X + (size_t)(rowOff + ar) * KX + (f * 32 - KT) + k0);
  }

  for (int halfc = 0; halfc < 2; halfc++) {
    __syncthreads();  // prior-half readers done before overwrite (no-op cost on 1st)
    for (int i = tid; i < NCH * (K / 8); i += 256) {
      int col = i / (K / 8);
      int kk = (i % (K / 8)) * 8;
      *(uint4*)(bs + col * KP + kk) =
          *(const uint4*)(Bt + (size_t)(halfc * NCH + col) * K + kk);
    }
    __syncthreads();

    for (int col0 = 0; col0 < NCH; col0 += 32) {
      f32x4 acc0 = {0.f, 0.f, 0.f, 0.f};
      f32x4 acc1 = {0.f, 0.f, 0.f, 0.f};
#pragma unroll
      for (int f = 0; f < K / 32; f++) {
        bf16x8 b0 = *(const bf16x8*)(bs + (col0 + m) * KP + f * 32 + k0);
        bf16x8 b1 = *(const bf16x8*)(bs + (col0 + 16 + m) * KP + f * 32 + k0);
        acc0 = __builtin_amdgcn_mfma_f32_16x16x32_bf16(afrag[f], b0, acc0, 0, 0, 0);
        acc1 = __builtin_amdgcn_mfma_f32_16x16x32_bf16(afrag[f], b1, acc1, 0, 0, 0);
      }
#pragma unroll
      for (int half = 0; half < 2; half++) {
        const f32x4& acc = half ? acc1 : acc0;
        const int col = halfc * NCH + col0 + half * 16 + m;
        float s1 = 0.f, s2 = 0.f;
#pragma unroll
        for (int r = 0; r < 4; r++) {
          int gr = rowbase + quad * 4 + r;
          if (gr < rows) {
            size_t g = (size_t)(rowOff + gr);
            u16 vq = f2bf(acc[r]);
            float v = bf2f(vq);
            s1 += v;
            s2 += v * v;
            if (NC == 64 || col < 64) O1[g * 64 + col] = vq;
            else O2[g * 64 + (col - 64)] = vq;
          }
        }
        // reduce the 64 block-rows for this col: quads live at lane m+16q
        s1 += __shfl_xor(s1, 16); s1 += __shfl_xor(s1, 32);
        s2 += __shfl_xor(s2, 16); s2 += __shfl_xor(s2, 32);
        if (lane < 16) { slds[wv][col][0] = s1; slds[wv][col][1] = s2; }
      }
    }
  }
  __syncthreads();
  if (tid < NC * 2) {
    int col = tid >> 1, which = tid & 1;
    float v = slds[0][col][which] + slds[1][col][which] + slds[2][col][which] +
              slds[3][col][which];
    int slot = ((NC > 64 && col >= 64) ? 128 : 0) + which * 64 + (col & 63);
    atomicAdd(&sums[slot], (double)v);
  }
}

// ---------------- bn finalize: one or two parameter sets per launch ----------------
__global__ void bn_finalize2(const double* __restrict__ sums, const float* __restrict__ gA,
                             const float* __restrict__ bA, const float* __restrict__ gB,
                             const float* __restrict__ bB, float* __restrict__ scales, int N) {
  int t = threadIdx.x;
  int set = t >> 6, ch = t & 63;
  if (set == 1 && gB == nullptr) return;
  const float* g = set ? gB : gA;
  const float* b = set ? bB : bA;
  double mean = sums[set * 128 + ch] / (double)N;
  double var = sums[set * 128 + 64 + ch] / (double)N - mean * mean;
  double inv = 1.0 / sqrt(var + (double)BN_EPS);
  float sc = (float)((double)g[ch] * inv);
  scales[set * 128 + ch] = sc;
  scales[set * 128 + 64 + ch] = b[ch] - (float)mean * sc;
}

// ---------------- h1pre -> elu(bn1(h1pre)) in place (bf16, gemm2's A tail) + fp8 copy
// h8 [N][64] (layer-2 gather table: 6.4 MB). 2 channels/thread.
__global__ __launch_bounds__(256) void bn_elu_inplace(u16* __restrict__ h,
                                                      u16* __restrict__ h8,
                                                      const float* __restrict__ sc,
                                                      int total2) {
  int idx = blockIdx.x * 256 + threadIdx.x;
  if (idx >= total2) return;
  int ch = (idx * 2) & 63;
  uint32 u = ((const uint32*)h)[idx];
  float v0 = __uint_as_float(u << 16);
  float v1 = __uint_as_float(u & 0xFFFF0000u);
  v0 = v0 * sc[ch] + sc[64 + ch];
  v1 = v1 * sc[ch + 1] + sc[64 + ch + 1];
  v0 = v0 > 0.f ? v0 : expm1f(v0);
  v1 = v1 > 0.f ? v1 : expm1f(v1);
  ((uint32*)h)[idx] = ((uint32)f2bf(v1) << 16) | (uint32)f2bf(v0);
  int p8 = __builtin_amdgcn_cvt_pk_fp8_f32(v0, v1, 0, false);  // byte0=v0, byte1=v1
  h8[idx] = (u16)(p8 & 0xFFFF);
}

// ---------------- epilogue: out = elu(bn2(h2pre) + bnS(skip)), 2 elems/thread ----------
__global__ __launch_bounds__(256) void final_k(const u16* __restrict__ h2pre,
                                               const u16* __restrict__ skip,
                                               const float* __restrict__ sc2,
                                               const float* __restrict__ scS,
                                               float* __restrict__ out, int total2) {
  int idx = blockIdx.x * 256 + threadIdx.x;
  if (idx >= total2) return;
  int ch = (idx * 2) & 63;
  uint32 uh = ((const uint32*)h2pre)[idx];
  uint32 us = ((const uint32*)skip)[idx];
  float h20 = __uint_as_float(uh << 16) * sc2[ch] + sc2[64 + ch];
  float h21 = __uint_as_float(uh & 0xFFFF0000u) * sc2[ch + 1] + sc2[64 + ch + 1];
  float s0 = __uint_as_float(us << 16) * scS[ch] + scS[64 + ch];
  float s1 = __uint_as_float(us & 0xFFFF0000u) * scS[ch + 1] + scS[64 + ch + 1];
  float v0 = h20 + s0, v1 = h21 + s1;
  v0 = v0 > 0.f ? v0 : expm1f(v0);
  v1 = v1 > 0.f ? v1 : expm1f(v1);
  ((float2*)out)[idx] = make_float2(v0, v1);
}

extern "C" void kernel_launch(void* const* d_in, const int* in_sizes, int n_in,
                              void* d_out, int out_size, void* d_ws, size_t ws_size,
                              hipStream_t stream) {
  const float* x     = (const float*)d_in[0];
  const int*   ei    = (const int*)d_in[1];
  const float* attr  = (const float*)d_in[2];
  const float* W1    = (const float*)d_in[3];
  const float* root1 = (const float*)d_in[4];
  const float* g1    = (const float*)d_in[5];
  const float* b1    = (const float*)d_in[6];
  const float* W2    = (const float*)d_in[7];
  const float* root2 = (const float*)d_in[8];
  const float* g2    = (const float*)d_in[9];
  const float* b2    = (const float*)d_in[10];
  const float* Wskip = (const float*)d_in[11];
  const float* gS    = (const float*)d_in[12];
  const float* bS    = (const float*)d_in[13];
  const int N = in_sizes[0] / 32;
  const int E = in_sizes[1] / 2;
  const int Nh = (N + 1) / 2;
  float* out = (float*)d_out;

  char* ws = (char*)d_ws;
  size_t off = 0;
  auto alloc = [&](size_t bytes) {
    void* p = ws + off;
    off = (off + bytes + 255) & ~(size_t)255;
    return p;
  };
  u16* B1t = (u16*)alloc(128 * 288 * 2);
  u16* B2t = (u16*)alloc(64 * 576 * 2);
  double* sums = (double*)alloc(6 * 64 * 8);    // [h1 | skip | h2] x {sum, sumsq}
  float* scales = (float*)alloc(6 * 64 * 4);    // [bn1 | bnS | bn2] x {scale, shift}
  int* indeg = (int*)alloc((size_t)N * 4);
  int* rowptr = (int*)alloc(((size_t)N + 1) * 4);
  int* part = (int*)alloc((size_t)N * 4);
  int* bsum = (int*)alloc(1024 * 4);
  int* rank = (int*)alloc((size_t)E * 4);                  // per-edge rank within dst
  uint4* emeta = (uint4*)alloc((size_t)E * 16);            // {src, fp16 u0|u1, fp16 u2, pad}
  u16* xbf = (u16*)alloc((size_t)N * 32 * 2);              // bf16 x (GEMM1 A-tail)
  uint32* x8 = (uint32*)alloc((size_t)N * 32);             // fp8 x (layer-1 gather, 3.2 MB)
  u16* h8 = (u16*)alloc((size_t)N * 64);                   // fp8 h1 (layer-2 gather table)
  u16* T = (u16*)alloc((size_t)(N + 2) * 256 * 2);         // T1 full [N][256] / T2 chunk [Nh][512]
  u16* h1 = (u16*)alloc((size_t)N * 64 * 2);               // h1pre -> elu(bn1()) in place
  u16* skip = (u16*)alloc((size_t)N * 64 * 2);             // x@Wskip (pre-BN)
  u16* h2 = (u16*)alloc((size_t)N * 64 * 2);               // h2pre
  if (off > ws_size) return;  // workspace too small: fail gracefully

  hipMemsetAsync(indeg, 0, (size_t)N * 4, stream);
  hipMemsetAsync(sums, 0, 6 * 64 * 8, stream);

  const int eblocks = (E + 255) / 256;
  const int nb = (N + 1023) / 1024;
  prep<<<(N * 4 + 255) / 256, 256, 0, stream>>>(W1, root1, Wskip, W2, root2, B1t, B2t,
                                                x, xbf, x8, N * 4);
  hist_dst<<<eblocks, 256, 0, stream>>>(ei, E, indeg, rank);
  scan_block<<<nb, 1024, 0, stream>>>(indeg, part, bsum, N);
  scan_top<<<1, 1024, 0, stream>>>(bsum, nb);
  scan_add<<<(N + 255) / 256, 256, 0, stream>>>(part, bsum, rowptr, N, E);
  edge_scatter<<<eblocks, 256, 0, stream>>>(ei, attr, rowptr, rank, E, emeta);

  // ---- layer 1: T1 = basis-weighted fp8-x aggregation; h1/skip = [T1 | xbf] @ B1t
  msg_accum<2, true><<<2048, 256, 0, stream>>>(x8, rowptr, (const u32x4*)emeta, 0, N, T);
  gemm_agg<256, 32, 128, 4><<<(N + 63) / 64, 256, 0, stream>>>(T, xbf, B1t, h1, skip, 0, N,
                                                               sums);
  bn_finalize2<<<1, 128, 0, stream>>>(sums, g1, b1, gS, bS, scales, N);  // bn1 + bnS
  bn_elu_inplace<<<(N * 32 + 255) / 256, 256, 0, stream>>>(h1, h8, scales, N * 32);

  // ---- layer 2 in two row-chunks (T2 chunk buffer = 51.2 MB); gathers fp8 h8 ----
  for (int cph = 0; cph < 2; cph++) {
    int r0 = cph ? Nh : 0;
    int r1 = cph ? N : Nh;
    msg_accum<4, true><<<2048, 256, 0, stream>>>(h8, rowptr, (const u32x4*)emeta, r0, r1, T);
    gemm_agg<512, 64, 64, 3><<<(r1 - r0 + 63) / 64, 256, 0, stream>>>(T, h1, B2t, h2,
                                                                      nullptr, r0, r1 - r0,
                                                                      sums + 4 * 64);
  }
  bn_finalize2<<<1, 64, 0, stream>>>(sums + 4 * 64, g2, b2, nullptr, nullptr,
                                     scales + 4 * 64, N);

  final_k<<<(N * 32 + 255) / 256, 256, 0, stream>>>(h2, skip, scales + 4 * 64,
                                                    scales + 2 * 64, out, N * 32);
}